// Round 2
// baseline (3197.456 us; speedup 1.0000x reference)
//
#include <hip/hip_runtime.h>
#include <math.h>

#define B_   16
#define S_   200
#define H_   400
#define V_   25000
#define T_   8
#define NS_  30
#define NB_  3
#define NSW_ 36
#define BS_  480   // NS_*B_

// ---------------- Tiled fp32 GEMM:  C[m,n] = sum_k A[m,k] * W[n,k] ----------------
// A: [M,K] row-major (lda=K), W: [N,K] row-major (ldb=K), C: row stride ldc.
// TM=TN=64, TK=16, 256 threads, each thread computes 4x4 outputs.
__global__ __launch_bounds__(256)
void gemm_nt(const float* __restrict__ A, const float* __restrict__ W,
             float* __restrict__ C, int M, int N, int K, long long ldc) {
    __shared__ __align__(16) float As[16][64];
    __shared__ __align__(16) float Bs[16][64];
    const int tid = threadIdx.x;
    const int tx = tid & 15, ty = tid >> 4;
    const int m0 = blockIdx.y * 64;
    const int n0 = blockIdx.x * 64;

    float acc[4][4] = {};

    const int ml = tid >> 2;          // 0..63
    const int kl = (tid & 3) * 4;     // 0,4,8,12

    for (int k0 = 0; k0 < K; k0 += 16) {
        float4 va = make_float4(0.f, 0.f, 0.f, 0.f);
        int m = m0 + ml;
        if (m < M) va = *reinterpret_cast<const float4*>(A + (long long)m * K + k0 + kl);
        As[kl + 0][ml] = va.x; As[kl + 1][ml] = va.y;
        As[kl + 2][ml] = va.z; As[kl + 3][ml] = va.w;

        float4 vb = make_float4(0.f, 0.f, 0.f, 0.f);
        int n = n0 + ml;
        if (n < N) vb = *reinterpret_cast<const float4*>(W + (long long)n * K + k0 + kl);
        Bs[kl + 0][ml] = vb.x; Bs[kl + 1][ml] = vb.y;
        Bs[kl + 2][ml] = vb.z; Bs[kl + 3][ml] = vb.w;

        __syncthreads();
        #pragma unroll
        for (int k = 0; k < 16; ++k) {
            float a[4], b[4];
            #pragma unroll
            for (int i = 0; i < 4; ++i) a[i] = As[k][ty + i * 16];
            #pragma unroll
            for (int j = 0; j < 4; ++j) b[j] = Bs[k][tx + j * 16];
            #pragma unroll
            for (int i = 0; i < 4; ++i)
                #pragma unroll
                for (int j = 0; j < 4; ++j)
                    acc[i][j] = fmaf(a[i], b[j], acc[i][j]);
        }
        __syncthreads();
    }

    #pragma unroll
    for (int i = 0; i < 4; ++i) {
        int m = m0 + ty + i * 16;
        if (m >= M) continue;
        #pragma unroll
        for (int j = 0; j < 4; ++j) {
            int n = n0 + tx + j * 16;
            if (n < N) C[(long long)m * ldc + n] = acc[i][j];
        }
    }
}

// ---------------- init: h0 and dec_in0 ----------------
__global__ void init_state(const float* __restrict__ eh, const float* __restrict__ sembW,
                           const int* __restrict__ dom, const int* __restrict__ sli,
                           float* __restrict__ hid, float* __restrict__ x) {
    int i = blockIdx.x * blockDim.x + threadIdx.x;
    if (i >= BS_ * H_) return;
    int row = i / H_, d = i - row * H_;
    int batch = row % B_, slot = row / B_;
    hid[i] = eh[batch * H_ + d];
    x[i]   = sembW[dom[slot] * H_ + d] + sembW[sli[slot] * H_ + d];
}

// ---------------- GRU elementwise ----------------
__global__ void gru_elem(const float* __restrict__ gx, const float* __restrict__ gh,
                         const float* __restrict__ bih, const float* __restrict__ bhh,
                         float* __restrict__ hid) {
    int i = blockIdx.x * blockDim.x + threadIdx.x;
    if (i >= BS_ * H_) return;
    int row = i / H_, d = i - row * H_;
    const float* gxr = gx + (long long)row * 3 * H_;
    const float* ghr = gh + (long long)row * 3 * H_;
    float r = gxr[d] + bih[d] + ghr[d] + bhh[d];
    r = 1.f / (1.f + expf(-r));
    float z = gxr[H_ + d] + bih[H_ + d] + ghr[H_ + d] + bhh[H_ + d];
    z = 1.f / (1.f + expf(-z));
    float n = gxr[2 * H_ + d] + bih[2 * H_ + d] + r * (ghr[2 * H_ + d] + bhh[2 * H_ + d]);
    n = tanhf(n);
    hid[i] = (1.f - z) * n + z * hid[i];
}

// ---------------- attention + switch (+gate head at t==0), one block per row ----------------
__global__ __launch_bounds__(256)
void attention(const float* __restrict__ hid, const float* __restrict__ x,
               const float* __restrict__ enc, const int* __restrict__ story,
               const float* __restrict__ Wr, const float* __restrict__ Wrb,
               const float* __restrict__ Wg, const float* __restrict__ Wgb,
               float* __restrict__ prob, float* __restrict__ ctx,
               float* __restrict__ sw_out, float* __restrict__ gate_out, int t) {
    const int row = blockIdx.x;
    const int batch = row % B_;
    const int tid = threadIdx.x;
    __shared__ __align__(16) float hs[H_];
    __shared__ __align__(16) float xs[H_];
    __shared__ __align__(16) float cs[H_];
    __shared__ float sc[S_];
    __shared__ float red[256];

    for (int d = tid; d < H_; d += 256) {
        hs[d] = hid[(long long)row * H_ + d];
        xs[d] = x[(long long)row * H_ + d];
    }
    __syncthreads();

    const float* encb = enc + (long long)batch * S_ * H_;
    for (int s = tid; s < S_; s += 256) {
        const float4* e = reinterpret_cast<const float4*>(encb + (long long)s * H_);
        float acc = 0.f;
        #pragma unroll 4
        for (int d4 = 0; d4 < H_ / 4; ++d4) {
            float4 ev = e[d4];
            float4 hv = *reinterpret_cast<const float4*>(&hs[d4 * 4]);
            acc += ev.x * hv.x + ev.y * hv.y + ev.z * hv.z + ev.w * hv.w;
        }
        sc[s] = (story[batch * S_ + s] == 0) ? -1e30f : acc;
    }
    __syncthreads();

    // softmax over S_=200
    float v = (tid < S_) ? sc[tid] : -1e30f;
    red[tid] = v; __syncthreads();
    for (int st = 128; st > 0; st >>= 1) {
        if (tid < st) red[tid] = fmaxf(red[tid], red[tid + st]);
        __syncthreads();
    }
    float mx = red[0]; __syncthreads();
    float e = 0.f;
    if (tid < S_) { e = expf(sc[tid] - mx); sc[tid] = e; }
    red[tid] = e; __syncthreads();
    for (int st = 128; st > 0; st >>= 1) {
        if (tid < st) red[tid] += red[tid + st];
        __syncthreads();
    }
    float inv = 1.f / red[0]; __syncthreads();
    if (tid < S_) { sc[tid] *= inv; prob[(long long)row * S_ + tid] = sc[tid]; }
    __syncthreads();

    // ctx = prob @ enc  (coalesced across d)
    for (int d = tid; d < H_; d += 256) {
        float acc = 0.f;
        for (int s = 0; s < S_; ++s) acc += sc[s] * encb[(long long)s * H_ + d];
        cs[d] = acc;
        ctx[(long long)row * H_ + d] = acc;
    }
    __syncthreads();

    // switch = sigmoid([hid|ctx|x] . Wr + b)
    float part = 0.f;
    for (int i = tid; i < 3 * H_; i += 256) {
        float xv = (i < H_) ? hs[i] : (i < 2 * H_) ? cs[i - H_] : xs[i - 2 * H_];
        part += xv * Wr[i];
    }
    red[tid] = part; __syncthreads();
    for (int st = 128; st > 0; st >>= 1) {
        if (tid < st) red[tid] += red[tid + st];
        __syncthreads();
    }
    if (tid == 0) sw_out[row] = 1.f / (1.f + expf(-(red[0] + Wrb[0])));

    // gate head, only at t==0 (uses ctx of first step)
    if (t == 0 && tid < NB_) {
        float acc = 0.f;
        for (int d = 0; d < H_; ++d) acc += cs[d] * Wg[tid * H_ + d];
        gate_out[(long long)row * NB_ + tid] = acc + Wgb[tid];
    }
}

// ---------------- teacher-forcing input gather ----------------
__global__ void x_update(const int* __restrict__ tb, const float* __restrict__ embW,
                         float* __restrict__ x, int t) {
    int i = blockIdx.x * blockDim.x + threadIdx.x;
    if (i >= BS_ * H_) return;
    int row = i / H_, d = i - row * H_;
    int batch = row % B_, slot = row / B_;
    int tok = tb[(batch * NS_ + slot) * T_ + t];
    x[i] = embW[(long long)tok * H_ + d];
}

// ---------------- in-place vocab softmax scaled by switch ----------------
__global__ __launch_bounds__(256)
void softmax_final(float* __restrict__ out, const float* __restrict__ sw, int t) {
    const int row = blockIdx.x;
    float* p = out + ((long long)row * T_ + t) * V_;
    const int tid = threadIdx.x;
    __shared__ float red[256];
    float mx = -1e30f;
    for (int v = tid; v < V_; v += 256) mx = fmaxf(mx, p[v]);
    red[tid] = mx; __syncthreads();
    for (int st = 128; st > 0; st >>= 1) {
        if (tid < st) red[tid] = fmaxf(red[tid], red[tid + st]);
        __syncthreads();
    }
    mx = red[0]; __syncthreads();
    float sum = 0.f;
    for (int v = tid; v < V_; v += 256) sum += expf(p[v] - mx);
    red[tid] = sum; __syncthreads();
    for (int st = 128; st > 0; st >>= 1) {
        if (tid < st) red[tid] += red[tid + st];
        __syncthreads();
    }
    float scale = sw[row] / red[0];
    for (int v = tid; v < V_; v += 256) p[v] = scale * expf(p[v] - mx);
}

// ---------------- pointer distribution scatter-add ----------------
__global__ void scatter_ctx(float* __restrict__ out, const float* __restrict__ prob,
                            const float* __restrict__ sw, const int* __restrict__ story,
                            int t) {
    int i = blockIdx.x * blockDim.x + threadIdx.x;
    if (i >= BS_ * S_) return;
    int row = i / S_, s = i - row * S_;
    int batch = row % B_;
    int tok = story[batch * S_ + s];
    float v = (1.f - sw[row]) * prob[(long long)row * S_ + s];
    atomicAdd(out + ((long long)row * T_ + t) * V_ + tok, v);
}

extern "C" void kernel_launch(void* const* d_in, const int* in_sizes, int n_in,
                              void* d_out, int out_size, void* d_ws, size_t ws_size,
                              hipStream_t stream) {
    const float* eh    = (const float*)d_in[0];
    const float* enc   = (const float*)d_in[1];
    const int*   story = (const int*)d_in[2];
    const int*   tb    = (const int*)d_in[3];
    const int*   dom   = (const int*)d_in[4];
    const int*   sli   = (const int*)d_in[5];
    const float* embW  = (const float*)d_in[6];
    const float* sembW = (const float*)d_in[7];
    const float* Wih   = (const float*)d_in[8];
    const float* Whh   = (const float*)d_in[9];
    const float* bih   = (const float*)d_in[10];
    const float* bhh   = (const float*)d_in[11];
    const float* Wr    = (const float*)d_in[12];
    const float* Wrb   = (const float*)d_in[13];
    const float* Wg    = (const float*)d_in[14];
    const float* Wgb   = (const float*)d_in[15];

    float* out = (float*)d_out;
    float* ws  = (float*)d_ws;

    float* gx   = ws;                     // [480,1200]
    float* gh   = gx + BS_ * 3 * H_;      // [480,1200]
    float* hid  = gh + BS_ * 3 * H_;      // [480,400]
    float* x    = hid + BS_ * H_;         // [480,400]
    float* ctx  = x + BS_ * H_;           // [480,400]
    float* prob = ctx + BS_ * H_;         // [480,200]
    float* sw   = prob + BS_ * S_;        // [480]
    float* gate_out = out + (long long)NS_ * B_ * T_ * V_;

    init_state<<<(BS_ * H_ + 255) / 256, 256, 0, stream>>>(eh, sembW, dom, sli, hid, x);

    dim3 gGates((3 * H_ + 63) / 64, (BS_ + 63) / 64);   // 19 x 8
    dim3 gVocab((V_ + 63) / 64, (BS_ + 63) / 64);       // 391 x 8

    for (int t = 0; t < T_; ++t) {
        gemm_nt<<<gGates, 256, 0, stream>>>(x,   Wih, gx, BS_, 3 * H_, H_, 3 * H_);
        gemm_nt<<<gGates, 256, 0, stream>>>(hid, Whh, gh, BS_, 3 * H_, H_, 3 * H_);
        gru_elem<<<(BS_ * H_ + 255) / 256, 256, 0, stream>>>(gx, gh, bih, bhh, hid);
        attention<<<BS_, 256, 0, stream>>>(hid, x, enc, story, Wr, Wrb, Wg, Wgb,
                                           prob, ctx, sw, gate_out, t);
        x_update<<<(BS_ * H_ + 255) / 256, 256, 0, stream>>>(tb, embW, x, t);
        // logits straight into the output slice (strided), then in-place softmax*switch
        gemm_nt<<<gVocab, 256, 0, stream>>>(hid, embW, out + (long long)t * V_,
                                            BS_, V_, H_, (long long)T_ * V_);
        softmax_final<<<BS_, 256, 0, stream>>>(out, sw, t);
        scatter_ctx<<<(BS_ * S_ + 255) / 256, 256, 0, stream>>>(out, prob, sw, story, t);
    }
}

// Round 4
// 1678.920 us; speedup vs baseline: 1.9045x; 1.9045x over previous
//
#include <hip/hip_runtime.h>
#include <math.h>

#define B_   16
#define S_   200
#define H_   400
#define V_   25000
#define T_   8
#define NS_  30
#define NB_  3
#define NSW_ 36
#define BS_  480   // NS_*B_

#define KP_  448   // K padded to 7*64 for BK=64 MFMA
#define MP_  512   // M padded to 4*128
#define NP_  25088 // N padded to 196*128
#define NTILE_ 196

typedef unsigned short u16;
typedef __attribute__((ext_vector_type(4))) float f32x4;
typedef __attribute__((ext_vector_type(8))) short short8;

__device__ __forceinline__ u16 f2bf(float f) {
    unsigned u = __float_as_uint(f);
    u += 0x7FFFu + ((u >> 16) & 1u);   // round-to-nearest-even
    return (u16)(u >> 16);
}

__device__ __forceinline__ void gload_lds16(const void* g, void* l) {
    __builtin_amdgcn_global_load_lds(
        (const __attribute__((address_space(1))) void*)g,
        (__attribute__((address_space(3))) void*)l, 16, 0, 0);
}

// ---------------- Tiled fp32 GEMM (gates + fallback path) ----------------
__global__ __launch_bounds__(256)
void gemm_nt(const float* __restrict__ A, const float* __restrict__ W,
             float* __restrict__ C, int M, int N, int K, long long ldc) {
    __shared__ __align__(16) float As[16][64];
    __shared__ __align__(16) float Bs[16][64];
    const int tid = threadIdx.x;
    const int tx = tid & 15, ty = tid >> 4;
    const int m0 = blockIdx.y * 64;
    const int n0 = blockIdx.x * 64;

    float acc[4][4] = {};
    const int ml = tid >> 2;
    const int kl = (tid & 3) * 4;

    for (int k0 = 0; k0 < K; k0 += 16) {
        float4 va = make_float4(0.f, 0.f, 0.f, 0.f);
        int m = m0 + ml;
        if (m < M) va = *reinterpret_cast<const float4*>(A + (long long)m * K + k0 + kl);
        As[kl + 0][ml] = va.x; As[kl + 1][ml] = va.y;
        As[kl + 2][ml] = va.z; As[kl + 3][ml] = va.w;

        float4 vb = make_float4(0.f, 0.f, 0.f, 0.f);
        int n = n0 + ml;
        if (n < N) vb = *reinterpret_cast<const float4*>(W + (long long)n * K + k0 + kl);
        Bs[kl + 0][ml] = vb.x; Bs[kl + 1][ml] = vb.y;
        Bs[kl + 2][ml] = vb.z; Bs[kl + 3][ml] = vb.w;

        __syncthreads();
        #pragma unroll
        for (int k = 0; k < 16; ++k) {
            float a[4], b[4];
            #pragma unroll
            for (int i = 0; i < 4; ++i) a[i] = As[k][ty + i * 16];
            #pragma unroll
            for (int j = 0; j < 4; ++j) b[j] = Bs[k][tx + j * 16];
            #pragma unroll
            for (int i = 0; i < 4; ++i)
                #pragma unroll
                for (int j = 0; j < 4; ++j)
                    acc[i][j] = fmaf(a[i], b[j], acc[i][j]);
        }
        __syncthreads();
    }

    #pragma unroll
    for (int i = 0; i < 4; ++i) {
        int m = m0 + ty + i * 16;
        if (m >= M) continue;
        #pragma unroll
        for (int j = 0; j < 4; ++j) {
            int n = n0 + tx + j * 16;
            if (n < N) C[(long long)m * ldc + n] = acc[i][j];
        }
    }
}

// ---------------- init: h0 and dec_in0 ----------------
__global__ void init_state(const float* __restrict__ eh, const float* __restrict__ sembW,
                           const int* __restrict__ dom, const int* __restrict__ sli,
                           float* __restrict__ hid, float* __restrict__ x) {
    int i = blockIdx.x * blockDim.x + threadIdx.x;
    if (i >= BS_ * H_) return;
    int row = i / H_, d = i - row * H_;
    int batch = row % B_, slot = row / B_;
    hid[i] = eh[batch * H_ + d];
    x[i]   = sembW[dom[slot] * H_ + d] + sembW[sli[slot] * H_ + d];
}

// ---------------- zero bf16-A pad region + per-t row sums ----------------
__global__ void zero_misc(u16* __restrict__ Ab, float* __restrict__ rowsum) {
    int i = blockIdx.x * blockDim.x + threadIdx.x;
    if (i < MP_ * KP_ / 8) {
        short8 z = {};
        *reinterpret_cast<short8*>(Ab + (size_t)i * 8) = z;
    }
    if (i < T_ * BS_) rowsum[i] = 0.f;
}

// ---------------- embW fp32 -> padded bf16 [NP_][KP_] ----------------
__global__ void conv_emb(const float* __restrict__ emb, u16* __restrict__ Bb) {
    int i = blockIdx.x * blockDim.x + threadIdx.x;   // over NP_ * (KP_/8)
    if (i >= NP_ * (KP_ / 8)) return;
    int row = i / (KP_ / 8), c8 = (i - row * (KP_ / 8)) * 8;
    short8 o = {};
    if (row < V_ && c8 < H_) {   // H_ % 8 == 0 so chunk fully in-range
        const float4* s = reinterpret_cast<const float4*>(emb + (size_t)row * H_ + c8);
        float4 a = s[0], b = s[1];
        o[0] = (short)f2bf(a.x); o[1] = (short)f2bf(a.y);
        o[2] = (short)f2bf(a.z); o[3] = (short)f2bf(a.w);
        o[4] = (short)f2bf(b.x); o[5] = (short)f2bf(b.y);
        o[6] = (short)f2bf(b.z); o[7] = (short)f2bf(b.w);
    }
    *reinterpret_cast<short8*>(Bb + (size_t)row * KP_ + c8) = o;
}

// ---------------- GRU elementwise (+ writes bf16 hid for MFMA) ----------------
__global__ void gru_elem(const float* __restrict__ gx, const float* __restrict__ gh,
                         const float* __restrict__ bih, const float* __restrict__ bhh,
                         float* __restrict__ hid, u16* __restrict__ Ab) {
    int i = blockIdx.x * blockDim.x + threadIdx.x;
    if (i >= BS_ * H_) return;
    int row = i / H_, d = i - row * H_;
    const float* gxr = gx + (long long)row * 3 * H_;
    const float* ghr = gh + (long long)row * 3 * H_;
    float r = gxr[d] + bih[d] + ghr[d] + bhh[d];
    r = 1.f / (1.f + expf(-r));
    float z = gxr[H_ + d] + bih[H_ + d] + ghr[H_ + d] + bhh[H_ + d];
    z = 1.f / (1.f + expf(-z));
    float n = gxr[2 * H_ + d] + bih[2 * H_ + d] + r * (ghr[2 * H_ + d] + bhh[2 * H_ + d]);
    n = tanhf(n);
    float h = (1.f - z) * n + z * hid[i];
    hid[i] = h;
    if (Ab) Ab[(size_t)row * KP_ + d] = f2bf(h);
}

// ---------------- attention + switch (+gate head at t==0) ----------------
__global__ __launch_bounds__(256)
void attention(const float* __restrict__ hid, const float* __restrict__ x,
               const float* __restrict__ enc, const int* __restrict__ story,
               const float* __restrict__ Wr, const float* __restrict__ Wrb,
               const float* __restrict__ Wg, const float* __restrict__ Wgb,
               float* __restrict__ prob, float* __restrict__ ctx,
               float* __restrict__ sw_out, float* __restrict__ gate_out, int t) {
    const int row = blockIdx.x;
    const int batch = row % B_;
    const int tid = threadIdx.x;
    __shared__ __align__(16) float hs[H_];
    __shared__ __align__(16) float xs[H_];
    __shared__ __align__(16) float cs[H_];
    __shared__ float sc[S_];
    __shared__ float red[256];

    for (int d = tid; d < H_; d += 256) {
        hs[d] = hid[(long long)row * H_ + d];
        xs[d] = x[(long long)row * H_ + d];
    }
    __syncthreads();

    const float* encb = enc + (long long)batch * S_ * H_;
    for (int s = tid; s < S_; s += 256) {
        const float4* e = reinterpret_cast<const float4*>(encb + (long long)s * H_);
        float acc = 0.f;
        #pragma unroll 4
        for (int d4 = 0; d4 < H_ / 4; ++d4) {
            float4 ev = e[d4];
            float4 hv = *reinterpret_cast<const float4*>(&hs[d4 * 4]);
            acc += ev.x * hv.x + ev.y * hv.y + ev.z * hv.z + ev.w * hv.w;
        }
        sc[s] = (story[batch * S_ + s] == 0) ? -1e30f : acc;
    }
    __syncthreads();

    float v = (tid < S_) ? sc[tid] : -1e30f;
    red[tid] = v; __syncthreads();
    for (int st = 128; st > 0; st >>= 1) {
        if (tid < st) red[tid] = fmaxf(red[tid], red[tid + st]);
        __syncthreads();
    }
    float mx = red[0]; __syncthreads();
    float e = 0.f;
    if (tid < S_) { e = expf(sc[tid] - mx); sc[tid] = e; }
    red[tid] = e; __syncthreads();
    for (int st = 128; st > 0; st >>= 1) {
        if (tid < st) red[tid] += red[tid + st];
        __syncthreads();
    }
    float inv = 1.f / red[0]; __syncthreads();
    if (tid < S_) { sc[tid] *= inv; prob[(long long)row * S_ + tid] = sc[tid]; }
    __syncthreads();

    for (int d = tid; d < H_; d += 256) {
        float acc = 0.f;
        for (int s = 0; s < S_; ++s) acc += sc[s] * encb[(long long)s * H_ + d];
        cs[d] = acc;
        ctx[(long long)row * H_ + d] = acc;
    }
    __syncthreads();

    float part = 0.f;
    for (int i = tid; i < 3 * H_; i += 256) {
        float xv = (i < H_) ? hs[i] : (i < 2 * H_) ? cs[i - H_] : xs[i - 2 * H_];
        part += xv * Wr[i];
    }
    red[tid] = part; __syncthreads();
    for (int st = 128; st > 0; st >>= 1) {
        if (tid < st) red[tid] += red[tid + st];
        __syncthreads();
    }
    if (tid == 0) sw_out[row] = 1.f / (1.f + expf(-(red[0] + Wrb[0])));

    if (t == 0 && tid < NB_) {
        float acc = 0.f;
        for (int d = 0; d < H_; ++d) acc += cs[d] * Wg[tid * H_ + d];
        gate_out[(long long)row * NB_ + tid] = acc + Wgb[tid];
    }
}

// ---------------- teacher-forcing input gather ----------------
__global__ void x_update(const int* __restrict__ tb, const float* __restrict__ embW,
                         float* __restrict__ x, int t) {
    int i = blockIdx.x * blockDim.x + threadIdx.x;
    if (i >= BS_ * H_) return;
    int row = i / H_, d = i - row * H_;
    int batch = row % B_, slot = row / B_;
    int tok = tb[(batch * NS_ + slot) * T_ + t];
    x[i] = embW[(long long)tok * H_ + d];
}

// ---------------- bf16 MFMA vocab GEMM, epilogue: exp + row-sum ----------------
// A: [MP_][KP_] bf16 (hid, zero-padded). B: [NP_][KP_] bf16 (embW, zero-padded).
// out[(m*T_+t)*V_ + n] = exp(logit); rowsum[t*BS_+m] += sums.
__global__ __launch_bounds__(256)
void vocab_mfma(const u16* __restrict__ A, const u16* __restrict__ Bm,
                float* __restrict__ out, float* __restrict__ rowsum, int t) {
    __shared__ u16 As[128 * 64];
    __shared__ u16 Bs[128 * 64];
    const int tid = threadIdx.x;
    const int wid = tid >> 6, lane = tid & 63;
    const int m0 = blockIdx.y * 128, n0 = blockIdx.x * 128;
    const int wr = wid >> 1, wc = wid & 1;   // 2x2 waves, 64x64 each

    f32x4 acc[4][4] = {};

    // staging: per wave 4 issues x 8 rows; lane covers (row = lane>>3, phys slot = lane&7)
    const int sslot = lane & 7;
    const int srow8 = (lane >> 3) & 7;
    const int lcol = (sslot ^ srow8) * 8;                    // pre-swizzled global col
    const u16* Ag = A + (size_t)(m0 + wid * 32 + (lane >> 3)) * KP_ + lcol;
    const u16* Bg = Bm + (size_t)(n0 + wid * 32 + (lane >> 3)) * KP_ + lcol;

    // fragment read offsets (row&7 == lane&7 for all fragment rows)
    const int lr = lane & 15, lg = lane >> 4, lx = lane & 7;
    const int sA0 = (lg ^ lx) * 8, sA1 = ((4 + lg) ^ lx) * 8;

    for (int k0 = 0; k0 < KP_; k0 += 64) {
        #pragma unroll
        for (int is = 0; is < 4; ++is) {
            gload_lds16(Ag + (size_t)is * 8 * KP_ + k0, &As[(wid * 32 + is * 8) * 64]);
            gload_lds16(Bg + (size_t)is * 8 * KP_ + k0, &Bs[(wid * 32 + is * 8) * 64]);
        }
        __syncthreads();   // drains vmcnt before barrier

        short8 af[4][2], bf[4][2];
        #pragma unroll
        for (int i = 0; i < 4; ++i) {
            int ra = (wr * 64 + i * 16 + lr) * 64;
            af[i][0] = *reinterpret_cast<const short8*>(&As[ra + sA0]);
            af[i][1] = *reinterpret_cast<const short8*>(&As[ra + sA1]);
            int rb = (wc * 64 + i * 16 + lr) * 64;
            bf[i][0] = *reinterpret_cast<const short8*>(&Bs[rb + sA0]);
            bf[i][1] = *reinterpret_cast<const short8*>(&Bs[rb + sA1]);
        }
        #pragma unroll
        for (int h = 0; h < 2; ++h)
            #pragma unroll
            for (int i = 0; i < 4; ++i)
                #pragma unroll
                for (int j = 0; j < 4; ++j)
                    acc[i][j] = __builtin_amdgcn_mfma_f32_16x16x32_bf16(
                        af[i][h], bf[j][h], acc[i][j], 0, 0, 0);
        __syncthreads();
    }

    // epilogue: exp, write, row-sum (shuffle-reduce over the 16-lane col group)
    const int m_base = m0 + wr * 64 + lg * 4;
    const int n_base = n0 + wc * 64 + lr;
    #pragma unroll
    for (int i = 0; i < 4; ++i) {
        #pragma unroll
        for (int r = 0; r < 4; ++r) {
            int m = m_base + i * 16 + r;
            float js = 0.f;
            #pragma unroll
            for (int j = 0; j < 4; ++j) {
                int n = n_base + j * 16;
                float e = __expf(acc[i][j][r]);
                if (m < BS_ && n < V_) {
                    out[((size_t)m * T_ + t) * V_ + n] = e;
                    js += e;
                }
            }
            js += __shfl_xor(js, 1);
            js += __shfl_xor(js, 2);
            js += __shfl_xor(js, 4);
            js += __shfl_xor(js, 8);
            if ((lane & 15) == 0 && m < BS_)
                atomicAdd(&rowsum[t * BS_ + m], js);
        }
    }
}

// ---------------- scale by switch/rowsum + pointer scatter, one block/row ----------------
__global__ __launch_bounds__(512)
void scale_scatter(float* __restrict__ out, const float* __restrict__ rowsum,
                   const float* __restrict__ sw, const float* __restrict__ prob,
                   const int* __restrict__ story, int t) {
    const int row = blockIdx.x;
    const int tid = threadIdx.x;
    float scl = sw[row] / rowsum[t * BS_ + row];
    float* p = out + ((size_t)row * T_ + t) * V_;
    for (int v = tid * 4; v < V_; v += 512 * 4) {    // V_ % 4 == 0
        float4* p4 = reinterpret_cast<float4*>(p + v);
        float4 x = *p4;
        x.x *= scl; x.y *= scl; x.z *= scl; x.w *= scl;
        *p4 = x;
    }
    __syncthreads();
    const int batch = row % B_;
    float om = 1.f - sw[row];
    for (int s = tid; s < S_; s += 512) {
        int tok = story[batch * S_ + s];
        atomicAdd(p + tok, om * prob[(size_t)row * S_ + s]);
    }
}

// ---------------- fallback softmax + scatter (fp32 path) ----------------
__global__ __launch_bounds__(256)
void softmax_final(float* __restrict__ out, const float* __restrict__ sw, int t) {
    const int row = blockIdx.x;
    float* p = out + ((long long)row * T_ + t) * V_;
    const int tid = threadIdx.x;
    __shared__ float red[256];
    float mx = -1e30f;
    for (int v = tid; v < V_; v += 256) mx = fmaxf(mx, p[v]);
    red[tid] = mx; __syncthreads();
    for (int st = 128; st > 0; st >>= 1) {
        if (tid < st) red[tid] = fmaxf(red[tid], red[tid + st]);
        __syncthreads();
    }
    mx = red[0]; __syncthreads();
    float sum = 0.f;
    for (int v = tid; v < V_; v += 256) sum += expf(p[v] - mx);
    red[tid] = sum; __syncthreads();
    for (int st = 128; st > 0; st >>= 1) {
        if (tid < st) red[tid] += red[tid + st];
        __syncthreads();
    }
    float scale = sw[row] / red[0];
    for (int v = tid; v < V_; v += 256) p[v] = scale * expf(p[v] - mx);
}

__global__ void scatter_ctx(float* __restrict__ out, const float* __restrict__ prob,
                            const float* __restrict__ sw, const int* __restrict__ story,
                            int t) {
    int i = blockIdx.x * blockDim.x + threadIdx.x;
    if (i >= BS_ * S_) return;
    int row = i / S_, s = i - row * S_;
    int batch = row % B_;
    int tok = story[batch * S_ + s];
    float v = (1.f - sw[row]) * prob[(long long)row * S_ + s];
    atomicAdd(out + ((long long)row * T_ + t) * V_ + tok, v);
}

extern "C" void kernel_launch(void* const* d_in, const int* in_sizes, int n_in,
                              void* d_out, int out_size, void* d_ws, size_t ws_size,
                              hipStream_t stream) {
    const float* eh    = (const float*)d_in[0];
    const float* enc   = (const float*)d_in[1];
    const int*   story = (const int*)d_in[2];
    const int*   tb    = (const int*)d_in[3];
    const int*   dom   = (const int*)d_in[4];
    const int*   sli   = (const int*)d_in[5];
    const float* embW  = (const float*)d_in[6];
    const float* sembW = (const float*)d_in[7];
    const float* Wih   = (const float*)d_in[8];
    const float* Whh   = (const float*)d_in[9];
    const float* bih   = (const float*)d_in[10];
    const float* bhh   = (const float*)d_in[11];
    const float* Wr    = (const float*)d_in[12];
    const float* Wrb   = (const float*)d_in[13];
    const float* Wg    = (const float*)d_in[14];
    const float* Wgb   = (const float*)d_in[15];

    float* out = (float*)d_out;
    float* ws  = (float*)d_ws;

    float* gx   = ws;                      // 576000
    float* gh   = gx + BS_ * 3 * H_;       // 576000
    float* hid  = gh + BS_ * 3 * H_;       // 192000
    float* x    = hid + BS_ * H_;          // 192000
    float* ctx  = x + BS_ * H_;            // 192000
    float* prob = ctx + BS_ * H_;          // 96000
    float* sw   = prob + BS_ * S_;         // 480
    float* rowsum = sw + BS_;              // T_*BS_ = 3840
    u16*   Ab   = (u16*)(rowsum + T_ * BS_);          // MP_*KP_ u16
    u16*   Bb   = Ab + (size_t)MP_ * KP_;             // NP_*KP_ u16
    size_t need = ((size_t)(Bb + (size_t)NP_ * KP_) - (size_t)ws);

    float* gate_out = out + (long long)NS_ * B_ * T_ * V_;
    const bool mfma_path = (ws_size >= need);

    init_state<<<(BS_ * H_ + 255) / 256, 256, 0, stream>>>(eh, sembW, dom, sli, hid, x);

    dim3 gGates((3 * H_ + 63) / 64, (BS_ + 63) / 64);
    dim3 gVocabF((V_ + 63) / 64, (BS_ + 63) / 64);
    dim3 gVocabM(NTILE_, MP_ / 128);

    if (mfma_path) {
        zero_misc<<<(MP_ * KP_ / 8 + 255) / 256, 256, 0, stream>>>(Ab, rowsum);
        conv_emb<<<(NP_ * (KP_ / 8) + 255) / 256, 256, 0, stream>>>(embW, Bb);
    }

    for (int t = 0; t < T_; ++t) {
        gemm_nt<<<gGates, 256, 0, stream>>>(x,   Wih, gx, BS_, 3 * H_, H_, 3 * H_);
        gemm_nt<<<gGates, 256, 0, stream>>>(hid, Whh, gh, BS_, 3 * H_, H_, 3 * H_);
        gru_elem<<<(BS_ * H_ + 255) / 256, 256, 0, stream>>>(gx, gh, bih, bhh, hid,
                                                             mfma_path ? Ab : (u16*)nullptr);
        attention<<<BS_, 256, 0, stream>>>(hid, x, enc, story, Wr, Wrb, Wg, Wgb,
                                           prob, ctx, sw, gate_out, t);
        x_update<<<(BS_ * H_ + 255) / 256, 256, 0, stream>>>(tb, embW, x, t);
        if (mfma_path) {
            vocab_mfma<<<gVocabM, 256, 0, stream>>>(Ab, Bb, out, rowsum, t);
            scale_scatter<<<BS_, 512, 0, stream>>>(out, rowsum, sw, prob, story, t);
        } else {
            gemm_nt<<<gVocabF, 256, 0, stream>>>(hid, embW, out + (long long)t * V_,
                                                 BS_, V_, H_, (long long)T_ * V_);
            softmax_final<<<BS_, 256, 0, stream>>>(out, sw, t);
            scatter_ctx<<<(BS_ * S_ + 255) / 256, 256, 0, stream>>>(out, prob, sw, story, t);
        }
    }
}

// Round 5
// 1252.995 us; speedup vs baseline: 2.5519x; 1.3399x over previous
//
#include <hip/hip_runtime.h>
#include <math.h>

#define B_   16
#define S_   200
#define H_   400
#define V_   25000
#define T_   8
#define NS_  30
#define NB_  3
#define NSW_ 36
#define BS_  480   // NS_*B_

#define KP_  448   // K padded (7 tiles of 64)
#define MP_  512   // M padded (4 tiles of 128)
#define NP_  25088 // vocab N padded (196 tiles of 128)
#define NG_  1280  // gates N padded (10 tiles of 128)

typedef unsigned short u16;
typedef __attribute__((ext_vector_type(4))) float f32x4;
typedef __attribute__((ext_vector_type(8))) short short8;

__device__ __forceinline__ u16 f2bf(float f) {
    unsigned u = __float_as_uint(f);
    u += 0x7FFFu + ((u >> 16) & 1u);   // round-to-nearest-even
    return (u16)(u >> 16);
}
__device__ __forceinline__ float bf2f(u16 v) {
    return __uint_as_float(((unsigned)v) << 16);
}

__device__ __forceinline__ void gload_lds16(const void* g, void* l) {
    __builtin_amdgcn_global_load_lds(
        (const __attribute__((address_space(1))) void*)g,
        (__attribute__((address_space(3))) void*)l, 16, 0, 0);
}

// Shared MFMA tile machinery: 128x128 tile, BK=64, 2x2 waves of 64x64,
// pre-swizzled global source -> linear LDS -> XOR-swizzled ds_read_b128.
#define MFMA_SETUP()                                                          \
    const int tid = threadIdx.x;                                              \
    const int wid = tid >> 6, lane = tid & 63;                                \
    const int wr = wid >> 1, wc = wid & 1;                                    \
    f32x4 acc[4][4] = {};                                                     \
    const int sslot = lane & 7;                                               \
    const int srow8 = (lane >> 3) & 7;                                        \
    const int lcol = (sslot ^ srow8) * 8;                                     \
    const int lr = lane & 15, lg = lane >> 4, lx = lane & 7;                  \
    const int sA0 = (lg ^ lx) * 8, sA1 = ((4 + lg) ^ lx) * 8;

#define STAGE_TILE(As_, Bs_, k0_)                                             \
    {                                                                         \
        _Pragma("unroll")                                                     \
        for (int is = 0; is < 4; ++is) {                                      \
            gload_lds16(Ag + (size_t)is * 8 * KP_ + (k0_),                    \
                        &(As_)[(wid * 32 + is * 8) * 64]);                    \
            gload_lds16(Bg + (size_t)is * 8 * KP_ + (k0_),                    \
                        &(Bs_)[(wid * 32 + is * 8) * 64]);                    \
        }                                                                     \
    }

#define COMPUTE_TILE(As_, Bs_)                                                \
    {                                                                         \
        short8 af[4][2], bfr[4][2];                                           \
        _Pragma("unroll")                                                     \
        for (int i = 0; i < 4; ++i) {                                         \
            int ra = (wr * 64 + i * 16 + lr) * 64;                            \
            af[i][0] = *reinterpret_cast<const short8*>(&(As_)[ra + sA0]);    \
            af[i][1] = *reinterpret_cast<const short8*>(&(As_)[ra + sA1]);    \
            int rb = (wc * 64 + i * 16 + lr) * 64;                            \
            bfr[i][0] = *reinterpret_cast<const short8*>(&(Bs_)[rb + sA0]);   \
            bfr[i][1] = *reinterpret_cast<const short8*>(&(Bs_)[rb + sA1]);   \
        }                                                                     \
        _Pragma("unroll")                                                     \
        for (int h = 0; h < 2; ++h)                                           \
            _Pragma("unroll")                                                 \
            for (int i = 0; i < 4; ++i)                                       \
                _Pragma("unroll")                                             \
                for (int j = 0; j < 4; ++j)                                   \
                    acc[i][j] = __builtin_amdgcn_mfma_f32_16x16x32_bf16(      \
                        af[i][h], bfr[j][h], acc[i][j], 0, 0, 0);             \
    }

// 2-phase double-buffered K loop over NT_K=7 tiles
#define MFMA_KLOOP()                                                          \
    STAGE_TILE(As[0], Bs[0], 0);                                              \
    __syncthreads();                                                          \
    _Pragma("unroll")                                                         \
    for (int kt = 0; kt < 6; ++kt) {                                          \
        const int cur = kt & 1, nxt = cur ^ 1;                                \
        STAGE_TILE(As[nxt], Bs[nxt], (kt + 1) * 64);                          \
        COMPUTE_TILE(As[cur], Bs[cur]);                                       \
        __syncthreads();                                                      \
    }                                                                         \
    COMPUTE_TILE(As[0], Bs[0]);

// ---------------- zero pads + rowsum ----------------
__global__ void zero_misc(u16* __restrict__ Ab, u16* __restrict__ Xb,
                          float* __restrict__ rowsum) {
    int i = blockIdx.x * blockDim.x + threadIdx.x;
    if (i < MP_ * KP_ / 8) {
        short8 z = {};
        *reinterpret_cast<short8*>(Ab + (size_t)i * 8) = z;
        *reinterpret_cast<short8*>(Xb + (size_t)i * 8) = z;
    }
    if (i < T_ * BS_) rowsum[i] = 0.f;
}

// ---------------- generic fp32[rows][400] -> bf16[prows][448] ----------------
__global__ void conv_bf16(const float* __restrict__ src, u16* __restrict__ dst,
                          int rows, int prows) {
    int i = blockIdx.x * blockDim.x + threadIdx.x;
    if (i >= prows * (KP_ / 8)) return;
    int row = i / (KP_ / 8), c8 = (i - row * (KP_ / 8)) * 8;
    short8 o = {};
    if (row < rows && c8 < H_) {
        const float4* s = reinterpret_cast<const float4*>(src + (size_t)row * H_ + c8);
        float4 a = s[0], b = s[1];
        o[0] = (short)f2bf(a.x); o[1] = (short)f2bf(a.y);
        o[2] = (short)f2bf(a.z); o[3] = (short)f2bf(a.w);
        o[4] = (short)f2bf(b.x); o[5] = (short)f2bf(b.y);
        o[6] = (short)f2bf(b.z); o[7] = (short)f2bf(b.w);
    }
    *reinterpret_cast<short8*>(dst + (size_t)row * KP_ + c8) = o;
}

// ---------------- init: h0 and dec_in0 (fp32 + bf16) ----------------
__global__ void init_state(const float* __restrict__ eh, const float* __restrict__ sembW,
                           const int* __restrict__ dom, const int* __restrict__ sli,
                           float* __restrict__ hid, float* __restrict__ x,
                           u16* __restrict__ Ab, u16* __restrict__ Xb) {
    int i = blockIdx.x * blockDim.x + threadIdx.x;
    if (i >= BS_ * H_) return;
    int row = i / H_, d = i - row * H_;
    int batch = row % B_, slot = row / B_;
    float h = eh[batch * H_ + d];
    float xv = sembW[dom[slot] * H_ + d] + sembW[sli[slot] * H_ + d];
    hid[i] = h;
    x[i] = xv;
    Ab[(size_t)row * KP_ + d] = f2bf(h);
    Xb[(size_t)row * KP_ + d] = f2bf(xv);
}

// ---------------- gates MFMA: z=0: gx = x@Wih^T, z=1: gh = hid@Whh^T ----------------
__global__ __launch_bounds__(256)
void gates_mfma(const u16* __restrict__ Xb, const u16* __restrict__ Ab,
                const u16* __restrict__ Wihb, const u16* __restrict__ Whhb,
                float* __restrict__ gx, float* __restrict__ gh) {
    __shared__ u16 As[2][128 * 64];
    __shared__ u16 Bs[2][128 * 64];
    const int z = blockIdx.z;
    const u16* A = z ? Ab : Xb;
    const u16* Bw = z ? Whhb : Wihb;
    float* C = z ? gh : gx;
    const int m0 = blockIdx.y * 128, n0 = blockIdx.x * 128;

    MFMA_SETUP();
    const u16* Ag = A + (size_t)(m0 + wid * 32 + (lane >> 3)) * KP_ + lcol;
    const u16* Bg = Bw + (size_t)(n0 + wid * 32 + (lane >> 3)) * KP_ + lcol;

    MFMA_KLOOP();

    const int m_base = m0 + wr * 64 + lg * 4;
    const int n_base = n0 + wc * 64 + lr;
    #pragma unroll
    for (int i = 0; i < 4; ++i)
        #pragma unroll
        for (int r = 0; r < 4; ++r) {
            int m = m_base + i * 16 + r;
            if (m >= BS_) continue;
            #pragma unroll
            for (int j = 0; j < 4; ++j) {
                int n = n_base + j * 16;
                if (n < 3 * H_) C[(size_t)m * 3 * H_ + n] = acc[i][j][r];
            }
        }
}

// ---------------- fused GRU + attention + switch + gate head + x_update ----------------
__global__ __launch_bounds__(256)
void attn_fused(const float* __restrict__ gx, const float* __restrict__ gh,
                const float* __restrict__ bih, const float* __restrict__ bhh,
                float* __restrict__ hid, u16* __restrict__ Ab,
                float* __restrict__ x, u16* __restrict__ Xb,
                const float* __restrict__ enc, const int* __restrict__ story,
                const int* __restrict__ tb, const float* __restrict__ embW,
                const float* __restrict__ Wr, const float* __restrict__ Wrb,
                const float* __restrict__ Wg, const float* __restrict__ Wgb,
                float* __restrict__ prob, float* __restrict__ sw_out,
                float* __restrict__ gate_out, int t) {
    const int row = blockIdx.x;
    const int batch = row % B_, slot = row / B_;
    const int tid = threadIdx.x;
    __shared__ __align__(16) float hs[H_];
    __shared__ __align__(16) float xs[H_];
    __shared__ __align__(16) float cs[H_];
    __shared__ float sc[S_];
    __shared__ float red[256];

    const float* gxr = gx + (size_t)row * 3 * H_;
    const float* ghr = gh + (size_t)row * 3 * H_;
    for (int d = tid; d < H_; d += 256) {
        float r = 1.f / (1.f + expf(-(gxr[d] + bih[d] + ghr[d] + bhh[d])));
        float z = 1.f / (1.f + expf(-(gxr[H_ + d] + bih[H_ + d] + ghr[H_ + d] + bhh[H_ + d])));
        float n = tanhf(gxr[2 * H_ + d] + bih[2 * H_ + d] + r * (ghr[2 * H_ + d] + bhh[2 * H_ + d]));
        float h = (1.f - z) * n + z * hid[(size_t)row * H_ + d];
        hs[d] = h;
        hid[(size_t)row * H_ + d] = h;
        Ab[(size_t)row * KP_ + d] = f2bf(h);
        xs[d] = x[(size_t)row * H_ + d];
    }
    __syncthreads();

    const float* encb = enc + (size_t)batch * S_ * H_;
    for (int s = tid; s < S_; s += 256) {
        const float4* e = reinterpret_cast<const float4*>(encb + (size_t)s * H_);
        float acc = 0.f;
        #pragma unroll 4
        for (int d4 = 0; d4 < H_ / 4; ++d4) {
            float4 ev = e[d4];
            float4 hv = *reinterpret_cast<const float4*>(&hs[d4 * 4]);
            acc += ev.x * hv.x + ev.y * hv.y + ev.z * hv.z + ev.w * hv.w;
        }
        sc[s] = (story[batch * S_ + s] == 0) ? -1e30f : acc;
    }
    __syncthreads();

    // softmax over S_=200
    float v = (tid < S_) ? sc[tid] : -1e30f;
    red[tid] = v; __syncthreads();
    for (int st = 128; st > 0; st >>= 1) {
        if (tid < st) red[tid] = fmaxf(red[tid], red[tid + st]);
        __syncthreads();
    }
    float mx = red[0]; __syncthreads();
    float e = 0.f;
    if (tid < S_) { e = expf(sc[tid] - mx); sc[tid] = e; }
    red[tid] = e; __syncthreads();
    for (int st = 128; st > 0; st >>= 1) {
        if (tid < st) red[tid] += red[tid + st];
        __syncthreads();
    }
    float inv = 1.f / red[0]; __syncthreads();
    if (tid < S_) { sc[tid] *= inv; prob[(size_t)row * S_ + tid] = sc[tid]; }
    __syncthreads();

    // ctx (LDS only)
    for (int d = tid; d < H_; d += 256) {
        float acc = 0.f;
        for (int s = 0; s < S_; ++s) acc += sc[s] * encb[(size_t)s * H_ + d];
        cs[d] = acc;
    }
    __syncthreads();

    // switch = sigmoid([hid|ctx|x] . Wr + b)
    float part = 0.f;
    for (int i = tid; i < 3 * H_; i += 256) {
        float xv = (i < H_) ? hs[i] : (i < 2 * H_) ? cs[i - H_] : xs[i - 2 * H_];
        part += xv * Wr[i];
    }
    red[tid] = part; __syncthreads();
    for (int st = 128; st > 0; st >>= 1) {
        if (tid < st) red[tid] += red[tid + st];
        __syncthreads();
    }
    if (tid == 0) sw_out[row] = 1.f / (1.f + expf(-(red[0] + Wrb[0])));

    if (t == 0 && tid < NB_) {
        float acc = 0.f;
        for (int d = 0; d < H_; ++d) acc += cs[d] * Wg[tid * H_ + d];
        gate_out[(size_t)row * NB_ + tid] = acc + Wgb[tid];
    }

    // teacher-forcing x update (input for step t+1)
    int tok = tb[(batch * NS_ + slot) * T_ + t];
    for (int d = tid; d < H_; d += 256) {
        float xv = embW[(size_t)tok * H_ + d];
        x[(size_t)row * H_ + d] = xv;
        Xb[(size_t)row * KP_ + d] = f2bf(xv);
    }
}

// ---------------- vocab MFMA, epilogue: exp -> bf16 pb + rowsum ----------------
__global__ __launch_bounds__(256)
void vocab_mfma(const u16* __restrict__ A, const u16* __restrict__ Bm,
                u16* __restrict__ pb, float* __restrict__ rowsum, int t) {
    __shared__ u16 As[2][128 * 64];
    __shared__ u16 Bs[2][128 * 64];
    const int m0 = blockIdx.y * 128, n0 = blockIdx.x * 128;

    MFMA_SETUP();
    const u16* Ag = A + (size_t)(m0 + wid * 32 + (lane >> 3)) * KP_ + lcol;
    const u16* Bg = Bm + (size_t)(n0 + wid * 32 + (lane >> 3)) * KP_ + lcol;

    MFMA_KLOOP();

    const int m_base = m0 + wr * 64 + lg * 4;
    const int n_base = n0 + wc * 64 + lr;
    #pragma unroll
    for (int i = 0; i < 4; ++i) {
        #pragma unroll
        for (int r = 0; r < 4; ++r) {
            int m = m_base + i * 16 + r;
            float js = 0.f;
            #pragma unroll
            for (int j = 0; j < 4; ++j) {
                int n = n_base + j * 16;
                float e = __expf(acc[i][j][r]);
                if (m < BS_ && n < V_) {
                    pb[(size_t)m * V_ + n] = f2bf(e);
                    js += e;
                }
            }
            js += __shfl_xor(js, 1);
            js += __shfl_xor(js, 2);
            js += __shfl_xor(js, 4);
            js += __shfl_xor(js, 8);
            if ((lane & 15) == 0 && m < BS_)
                atomicAdd(&rowsum[t * BS_ + m], js);
        }
    }
}

// ---------------- scale (sw/rowsum) + pointer scatter, one block/row ----------------
__global__ __launch_bounds__(512)
void scale_scatter(float* __restrict__ out, const u16* __restrict__ pb,
                   const float* __restrict__ rowsum, const float* __restrict__ sw,
                   const float* __restrict__ prob, const int* __restrict__ story,
                   int t) {
    const int row = blockIdx.x;
    const int tid = threadIdx.x;
    float scl = sw[row] / rowsum[t * BS_ + row];
    const u16* ps = pb + (size_t)row * V_;
    float* p = out + ((size_t)row * T_ + t) * V_;
    for (int v = tid * 8; v < V_; v += 512 * 8) {      // V_ % 8 == 0
        short8 in = *reinterpret_cast<const short8*>(ps + v);
        float4 o0, o1;
        o0.x = bf2f((u16)in[0]) * scl; o0.y = bf2f((u16)in[1]) * scl;
        o0.z = bf2f((u16)in[2]) * scl; o0.w = bf2f((u16)in[3]) * scl;
        o1.x = bf2f((u16)in[4]) * scl; o1.y = bf2f((u16)in[5]) * scl;
        o1.z = bf2f((u16)in[6]) * scl; o1.w = bf2f((u16)in[7]) * scl;
        *reinterpret_cast<float4*>(p + v) = o0;
        *reinterpret_cast<float4*>(p + v + 4) = o1;
    }
    __syncthreads();
    const int batch = row % B_;
    float om = 1.f - sw[row];
    for (int s = tid; s < S_; s += 512) {
        int tok = story[batch * S_ + s];
        atomicAdd(p + tok, om * prob[(size_t)row * S_ + s]);
    }
}

extern "C" void kernel_launch(void* const* d_in, const int* in_sizes, int n_in,
                              void* d_out, int out_size, void* d_ws, size_t ws_size,
                              hipStream_t stream) {
    const float* eh    = (const float*)d_in[0];
    const float* enc   = (const float*)d_in[1];
    const int*   story = (const int*)d_in[2];
    const int*   tb    = (const int*)d_in[3];
    const int*   dom   = (const int*)d_in[4];
    const int*   sli   = (const int*)d_in[5];
    const float* embW  = (const float*)d_in[6];
    const float* sembW = (const float*)d_in[7];
    const float* Wih   = (const float*)d_in[8];
    const float* Whh   = (const float*)d_in[9];
    const float* bih   = (const float*)d_in[10];
    const float* bhh   = (const float*)d_in[11];
    const float* Wr    = (const float*)d_in[12];
    const float* Wrb   = (const float*)d_in[13];
    const float* Wg    = (const float*)d_in[14];
    const float* Wgb   = (const float*)d_in[15];

    float* out = (float*)d_out;
    float* ws  = (float*)d_ws;

    float* gx     = ws;                    // [480][1200]
    float* gh     = gx + BS_ * 3 * H_;
    float* hid    = gh + BS_ * 3 * H_;     // [480][400]
    float* x      = hid + BS_ * H_;
    float* prob   = x + BS_ * H_;          // [480][200]
    float* sw     = prob + BS_ * S_;       // [480]
    float* rowsum = sw + BS_;              // [T_*BS_]
    u16* Ab   = (u16*)(rowsum + T_ * BS_); // [MP_][KP_]
    u16* Xb   = Ab + (size_t)MP_ * KP_;    // [MP_][KP_]
    u16* Wihb = Xb + (size_t)MP_ * KP_;    // [NG_][KP_]
    u16* Whhb = Wihb + (size_t)NG_ * KP_;  // [NG_][KP_]
    u16* Bb   = Whhb + (size_t)NG_ * KP_;  // [NP_][KP_]
    u16* pb   = Bb + (size_t)NP_ * KP_;    // [BS_][V_]
    size_t need = (size_t)((char*)(pb + (size_t)BS_ * V_) - (char*)ws);
    if (ws_size < need) return;            // fail loudly in validation

    float* gate_out = out + (size_t)NS_ * B_ * T_ * V_;

    zero_misc<<<(MP_ * KP_ / 8 + 255) / 256, 256, 0, stream>>>(Ab, Xb, rowsum);
    conv_bf16<<<(NP_ * (KP_ / 8) + 255) / 256, 256, 0, stream>>>(embW, Bb, V_, NP_);
    conv_bf16<<<(NG_ * (KP_ / 8) + 255) / 256, 256, 0, stream>>>(Wih, Wihb, 3 * H_, NG_);
    conv_bf16<<<(NG_ * (KP_ / 8) + 255) / 256, 256, 0, stream>>>(Whh, Whhb, 3 * H_, NG_);
    init_state<<<(BS_ * H_ + 255) / 256, 256, 0, stream>>>(eh, sembW, dom, sli, hid, x, Ab, Xb);

    dim3 gGates(NG_ / 128, MP_ / 128, 2);   // 10 x 4 x 2
    dim3 gVocab(NP_ / 128, MP_ / 128);      // 196 x 4

    for (int t = 0; t < T_; ++t) {
        gates_mfma<<<gGates, 256, 0, stream>>>(Xb, Ab, Wihb, Whhb, gx, gh);
        attn_fused<<<BS_, 256, 0, stream>>>(gx, gh, bih, bhh, hid, Ab, x, Xb,
                                            enc, story, tb, embW, Wr, Wrb, Wg, Wgb,
                                            prob, sw, gate_out, t);
        vocab_mfma<<<gVocab, 256, 0, stream>>>(Ab, Bb, pb, rowsum, t);
        scale_scatter<<<BS_, 512, 0, stream>>>(out, pb, rowsum, sw, prob, story, t);
    }
}

// Round 6
// 1251.999 us; speedup vs baseline: 2.5539x; 1.0008x over previous
//
#include <hip/hip_runtime.h>
#include <math.h>

#define B_   16
#define S_   200
#define H_   400
#define V_   25000
#define T_   8
#define NS_  30
#define NB_  3
#define NSW_ 36
#define BS_  480   // NS_*B_

#define KP_  448   // K padded (7 tiles of 64)
#define MP_  512   // M padded (4 tiles of 128)
#define NP_  25088 // vocab N padded (196 tiles of 128)
#define NG_  1280  // gates N padded (10 tiles of 128)
#define MA_  3840  // T_*BS_ (30 tiles of 128)
#define NVT_ (NP_/128)   // 196 vocab n-tiles

typedef unsigned short u16;
typedef __attribute__((ext_vector_type(4))) float f32x4;
typedef __attribute__((ext_vector_type(8))) short short8;

__device__ __forceinline__ u16 f2bf(float f) {
    unsigned u = __float_as_uint(f);
    u += 0x7FFFu + ((u >> 16) & 1u);   // round-to-nearest-even
    return (u16)(u >> 16);
}
__device__ __forceinline__ float bf2f(u16 v) {
    return __uint_as_float(((unsigned)v) << 16);
}

__device__ __forceinline__ void gload_lds16(const void* g, void* l) {
    __builtin_amdgcn_global_load_lds(
        (const __attribute__((address_space(1))) void*)g,
        (__attribute__((address_space(3))) void*)l, 16, 0, 0);
}

// 128x128 tile, BK=64, 2x2 waves of 64x64; pre-swizzled global source ->
// linear LDS (global_load_lds) -> XOR-swizzled ds_read_b128 (rule #21 pair).
#define MFMA_SETUP()                                                          \
    const int tid = threadIdx.x;                                              \
    const int wid = tid >> 6, lane = tid & 63;                                \
    const int wr = wid >> 1, wc = wid & 1;                                    \
    f32x4 acc[4][4] = {};                                                     \
    const int sslot = lane & 7;                                               \
    const int srow8 = (lane >> 3) & 7;                                        \
    const int lcol = (sslot ^ srow8) * 8;                                     \
    const int lr = lane & 15, lg = lane >> 4, lx = lane & 7;                  \
    const int sA0 = (lg ^ lx) * 8, sA1 = ((4 + lg) ^ lx) * 8;

#define STAGE_TILE(As_, Bs_, k0_)                                             \
    {                                                                         \
        _Pragma("unroll")                                                     \
        for (int is = 0; is < 4; ++is) {                                      \
            gload_lds16(Ag + (size_t)is * 8 * KP_ + (k0_),                    \
                        &(As_)[(wid * 32 + is * 8) * 64]);                    \
            gload_lds16(Bg + (size_t)is * 8 * KP_ + (k0_),                    \
                        &(Bs_)[(wid * 32 + is * 8) * 64]);                    \
        }                                                                     \
    }

#define COMPUTE_TILE(As_, Bs_)                                                \
    {                                                                         \
        short8 af[4][2], bfr[4][2];                                           \
        _Pragma("unroll")                                                     \
        for (int i = 0; i < 4; ++i) {                                         \
            int ra = (wr * 64 + i * 16 + lr) * 64;                            \
            af[i][0] = *reinterpret_cast<const short8*>(&(As_)[ra + sA0]);    \
            af[i][1] = *reinterpret_cast<const short8*>(&(As_)[ra + sA1]);    \
            int rb = (wc * 64 + i * 16 + lr) * 64;                            \
            bfr[i][0] = *reinterpret_cast<const short8*>(&(Bs_)[rb + sA0]);   \
            bfr[i][1] = *reinterpret_cast<const short8*>(&(Bs_)[rb + sA1]);   \
        }                                                                     \
        _Pragma("unroll")                                                     \
        for (int h = 0; h < 2; ++h)                                           \
            _Pragma("unroll")                                                 \
            for (int i = 0; i < 4; ++i)                                       \
                _Pragma("unroll")                                             \
                for (int j = 0; j < 4; ++j)                                   \
                    acc[i][j] = __builtin_amdgcn_mfma_f32_16x16x32_bf16(      \
                        af[i][h], bfr[j][h], acc[i][j], 0, 0, 0);             \
    }

// 2-phase double-buffered K loop over 7 tiles (T3-minimum: STAGE next, then
// compute current; one barrier per tile drains both)
#define MFMA_KLOOP()                                                          \
    STAGE_TILE(As[0], Bs[0], 0);                                              \
    __syncthreads();                                                          \
    _Pragma("unroll")                                                         \
    for (int kt = 0; kt < 6; ++kt) {                                          \
        const int cur = kt & 1, nxt = cur ^ 1;                                \
        STAGE_TILE(As[nxt], Bs[nxt], (kt + 1) * 64);                          \
        COMPUTE_TILE(As[cur], Bs[cur]);                                       \
        __syncthreads();                                                      \
    }                                                                         \
    COMPUTE_TILE(As[0], Bs[0]);

// ---------------- zero Ab (incl pads) + rowsum ----------------
__global__ void zero_misc(u16* __restrict__ Ab, float* __restrict__ rowsum) {
    int i = blockIdx.x * blockDim.x + threadIdx.x;
    if (i < MP_ * KP_ / 8) {
        short8 z = {};
        *reinterpret_cast<short8*>(Ab + (size_t)i * 8) = z;
    }
    if (i < T_ * BS_) rowsum[i] = 0.f;
}

// ---------------- fp32[rows][400] -> bf16[prows][448] ----------------
__global__ void conv_bf16(const float* __restrict__ src, u16* __restrict__ dst,
                          int rows, int prows) {
    int i = blockIdx.x * blockDim.x + threadIdx.x;
    if (i >= prows * (KP_ / 8)) return;
    int row = i / (KP_ / 8), c8 = (i - row * (KP_ / 8)) * 8;
    short8 o = {};
    if (row < rows && c8 < H_) {
        const float4* s = reinterpret_cast<const float4*>(src + (size_t)row * H_ + c8);
        float4 a = s[0], b = s[1];
        o[0] = (short)f2bf(a.x); o[1] = (short)f2bf(a.y);
        o[2] = (short)f2bf(a.z); o[3] = (short)f2bf(a.w);
        o[4] = (short)f2bf(b.x); o[5] = (short)f2bf(b.y);
        o[6] = (short)f2bf(b.z); o[7] = (short)f2bf(b.w);
    }
    *reinterpret_cast<short8*>(dst + (size_t)row * KP_ + c8) = o;
}

// ---------------- all-steps teacher-forcing inputs: x_all fp32 + Xb_all bf16 ----------------
__global__ void xall_prep(const int* __restrict__ tb, const float* __restrict__ embW,
                          const float* __restrict__ sembW,
                          const int* __restrict__ dom, const int* __restrict__ sli,
                          float* __restrict__ x_all, u16* __restrict__ Xb_all) {
    int i = blockIdx.x * blockDim.x + threadIdx.x;   // over MA_ * 56
    if (i >= MA_ * (KP_ / 8)) return;
    int row = i / (KP_ / 8), c8 = (i - row * (KP_ / 8)) * 8;
    int t = row / BS_, r = row - t * BS_;
    int batch = r % B_, slot = r / B_;
    short8 o = {};
    if (c8 < H_) {
        float4 a, b;
        if (t == 0) {
            const float4* s0 = reinterpret_cast<const float4*>(sembW + dom[slot] * H_ + c8);
            const float4* s1 = reinterpret_cast<const float4*>(sembW + sli[slot] * H_ + c8);
            float4 x0 = s0[0], x1 = s0[1], y0 = s1[0], y1 = s1[1];
            a = make_float4(x0.x + y0.x, x0.y + y0.y, x0.z + y0.z, x0.w + y0.w);
            b = make_float4(x1.x + y1.x, x1.y + y1.y, x1.z + y1.z, x1.w + y1.w);
        } else {
            int tok = tb[(batch * NS_ + slot) * T_ + (t - 1)];
            const float4* s = reinterpret_cast<const float4*>(embW + (size_t)tok * H_ + c8);
            a = s[0]; b = s[1];
        }
        o[0] = (short)f2bf(a.x); o[1] = (short)f2bf(a.y);
        o[2] = (short)f2bf(a.z); o[3] = (short)f2bf(a.w);
        o[4] = (short)f2bf(b.x); o[5] = (short)f2bf(b.y);
        o[6] = (short)f2bf(b.z); o[7] = (short)f2bf(b.w);
        *reinterpret_cast<float4*>(x_all + (size_t)row * H_ + c8) = a;
        *reinterpret_cast<float4*>(x_all + (size_t)row * H_ + c8 + 4) = b;
    }
    *reinterpret_cast<short8*>(Xb_all + (size_t)row * KP_ + c8) = o;
}

// ---------------- init: h0 fp32 + bf16 ----------------
__global__ void init_state(const float* __restrict__ eh, float* __restrict__ hid,
                           u16* __restrict__ Ab) {
    int i = blockIdx.x * blockDim.x + threadIdx.x;
    if (i >= BS_ * H_) return;
    int row = i / H_, d = i - row * H_;
    int batch = row % B_;
    float h = eh[batch * H_ + d];
    hid[i] = h;
    Ab[(size_t)row * KP_ + d] = f2bf(h);
}

// ---------------- generic bf16 MFMA GEMM, fp32 out ----------------
__global__ __launch_bounds__(256)
void gemm_f32out(const u16* __restrict__ A, const u16* __restrict__ Bw,
                 float* __restrict__ C, int Mlim, int Nlim, int ldc) {
    __shared__ u16 As[2][128 * 64];
    __shared__ u16 Bs[2][128 * 64];
    const int m0 = blockIdx.y * 128, n0 = blockIdx.x * 128;
    MFMA_SETUP();
    const u16* Ag = A + (size_t)(m0 + wid * 32 + (lane >> 3)) * KP_ + lcol;
    const u16* Bg = Bw + (size_t)(n0 + wid * 32 + (lane >> 3)) * KP_ + lcol;
    MFMA_KLOOP();
    const int m_base = m0 + wr * 64 + lg * 4;
    const int n_base = n0 + wc * 64 + lr;
    #pragma unroll
    for (int i = 0; i < 4; ++i)
        #pragma unroll
        for (int r = 0; r < 4; ++r) {
            int m = m_base + i * 16 + r;
            if (m >= Mlim) continue;
            #pragma unroll
            for (int j = 0; j < 4; ++j) {
                int n = n_base + j * 16;
                if (n < Nlim) C[(size_t)m * ldc + n] = acc[i][j][r];
            }
        }
}

// ---------------- vocab MFMA (exp->pb + rowsum) fused with gh GEMM for next step ----------------
__global__ __launch_bounds__(256)
void vocab_gh(const u16* __restrict__ A, const u16* __restrict__ Bb,
              const u16* __restrict__ Whhb, u16* __restrict__ pb,
              float* __restrict__ rowsum, float* __restrict__ gh, int t) {
    __shared__ u16 As[2][128 * 64];
    __shared__ u16 Bs[2][128 * 64];
    const bool isv = (blockIdx.x < NVT_);
    const int m0 = blockIdx.y * 128;
    const int n0 = (isv ? blockIdx.x : (blockIdx.x - NVT_)) * 128;
    const u16* Bsrc = isv ? Bb : Whhb;

    MFMA_SETUP();
    const u16* Ag = A + (size_t)(m0 + wid * 32 + (lane >> 3)) * KP_ + lcol;
    const u16* Bg = Bsrc + (size_t)(n0 + wid * 32 + (lane >> 3)) * KP_ + lcol;
    MFMA_KLOOP();

    const int m_base = m0 + wr * 64 + lg * 4;
    const int n_base = n0 + wc * 64 + lr;
    if (isv) {
        #pragma unroll
        for (int i = 0; i < 4; ++i) {
            #pragma unroll
            for (int r = 0; r < 4; ++r) {
                int m = m_base + i * 16 + r;
                float js = 0.f;
                #pragma unroll
                for (int j = 0; j < 4; ++j) {
                    int n = n_base + j * 16;
                    float e = __expf(acc[i][j][r]);
                    if (m < BS_ && n < V_) {
                        pb[(size_t)m * V_ + n] = f2bf(e);
                        js += e;
                    }
                }
                js += __shfl_xor(js, 1);
                js += __shfl_xor(js, 2);
                js += __shfl_xor(js, 4);
                js += __shfl_xor(js, 8);
                if ((lane & 15) == 0 && m < BS_)
                    atomicAdd(&rowsum[t * BS_ + m], js);
            }
        }
    } else {
        #pragma unroll
        for (int i = 0; i < 4; ++i)
            #pragma unroll
            for (int r = 0; r < 4; ++r) {
                int m = m_base + i * 16 + r;
                if (m >= BS_) continue;
                #pragma unroll
                for (int j = 0; j < 4; ++j) {
                    int n = n_base + j * 16;
                    if (n < 3 * H_) gh[(size_t)m * 3 * H_ + n] = acc[i][j][r];
                }
            }
    }
}

// ---------------- fused: [scale+scatter of step t-1] + GRU + attention + switch ----------------
__global__ __launch_bounds__(256)
void attn_fused(const float* __restrict__ gx_all, const float* __restrict__ gh,
                const float* __restrict__ bih, const float* __restrict__ bhh,
                float* __restrict__ hid, u16* __restrict__ Ab,
                const float* __restrict__ x_all,
                const float* __restrict__ enc, const int* __restrict__ story,
                const float* __restrict__ Wr, const float* __restrict__ Wrb,
                const float* __restrict__ Wg, const float* __restrict__ Wgb,
                float* __restrict__ prob, float* __restrict__ sw_out,
                float* __restrict__ gate_out,
                float* __restrict__ out, const u16* __restrict__ pb,
                const float* __restrict__ rowsum, int t) {
    const int row = blockIdx.x;
    const int batch = row % B_;
    const int tid = threadIdx.x;
    __shared__ __align__(16) float hs[H_];
    __shared__ __align__(16) float xs[H_];
    __shared__ __align__(16) float cs[H_];
    __shared__ float sc[S_];
    __shared__ float red[256];

    // ---- preamble: finalize step t-1's output for this row ----
    if (t > 0) {
        float swv = sw_out[row];                    // sw(t-1), not yet overwritten
        float scl = swv / rowsum[(t - 1) * BS_ + row];
        const u16* ps = pb + (size_t)row * V_;
        float* p = out + ((size_t)row * T_ + (t - 1)) * V_;
        for (int v = tid * 8; v < V_; v += 256 * 8) {       // V_ % 8 == 0
            short8 in = *reinterpret_cast<const short8*>(ps + v);
            float4 o0, o1;
            o0.x = bf2f((u16)in[0]) * scl; o0.y = bf2f((u16)in[1]) * scl;
            o0.z = bf2f((u16)in[2]) * scl; o0.w = bf2f((u16)in[3]) * scl;
            o1.x = bf2f((u16)in[4]) * scl; o1.y = bf2f((u16)in[5]) * scl;
            o1.z = bf2f((u16)in[6]) * scl; o1.w = bf2f((u16)in[7]) * scl;
            *reinterpret_cast<float4*>(p + v) = o0;
            *reinterpret_cast<float4*>(p + v + 4) = o1;
        }
        __syncthreads();                            // scale done before scatter
        float om = 1.f - swv;
        for (int s = tid; s < S_; s += 256) {
            int tok = story[batch * S_ + s];
            atomicAdd(p + tok, om * prob[(size_t)row * S_ + s]);   // prob(t-1)
        }
    }

    // ---- GRU cell -> hs (+ global hid, bf16 Ab) ----
    const float* gxr = gx_all + ((size_t)t * BS_ + row) * 3 * H_;
    const float* ghr = gh + (size_t)row * 3 * H_;
    const float* xr  = x_all + ((size_t)t * BS_ + row) * H_;
    for (int d = tid; d < H_; d += 256) {
        float r = 1.f / (1.f + expf(-(gxr[d] + bih[d] + ghr[d] + bhh[d])));
        float z = 1.f / (1.f + expf(-(gxr[H_ + d] + bih[H_ + d] + ghr[H_ + d] + bhh[H_ + d])));
        float n = tanhf(gxr[2 * H_ + d] + bih[2 * H_ + d] + r * (ghr[2 * H_ + d] + bhh[2 * H_ + d]));
        float h = (1.f - z) * n + z * hid[(size_t)row * H_ + d];
        hs[d] = h;
        hid[(size_t)row * H_ + d] = h;
        Ab[(size_t)row * KP_ + d] = f2bf(h);
        xs[d] = xr[d];
    }
    __syncthreads();

    // ---- scores ----
    const float* encb = enc + (size_t)batch * S_ * H_;
    for (int s = tid; s < S_; s += 256) {
        const float4* e = reinterpret_cast<const float4*>(encb + (size_t)s * H_);
        float acc = 0.f;
        #pragma unroll 4
        for (int d4 = 0; d4 < H_ / 4; ++d4) {
            float4 ev = e[d4];
            float4 hv = *reinterpret_cast<const float4*>(&hs[d4 * 4]);
            acc += ev.x * hv.x + ev.y * hv.y + ev.z * hv.z + ev.w * hv.w;
        }
        sc[s] = (story[batch * S_ + s] == 0) ? -1e30f : acc;
    }
    __syncthreads();

    // ---- softmax over S_=200 ----
    float v = (tid < S_) ? sc[tid] : -1e30f;
    red[tid] = v; __syncthreads();
    for (int st = 128; st > 0; st >>= 1) {
        if (tid < st) red[tid] = fmaxf(red[tid], red[tid + st]);
        __syncthreads();
    }
    float mx = red[0]; __syncthreads();
    float e = 0.f;
    if (tid < S_) { e = expf(sc[tid] - mx); sc[tid] = e; }
    red[tid] = e; __syncthreads();
    for (int st = 128; st > 0; st >>= 1) {
        if (tid < st) red[tid] += red[tid + st];
        __syncthreads();
    }
    float inv = 1.f / red[0]; __syncthreads();
    if (tid < S_) { sc[tid] *= inv; prob[(size_t)row * S_ + tid] = sc[tid]; }
    __syncthreads();

    // ---- ctx (LDS only) ----
    for (int d = tid; d < H_; d += 256) {
        float acc = 0.f;
        #pragma unroll 4
        for (int s = 0; s < S_; ++s) acc += sc[s] * encb[(size_t)s * H_ + d];
        cs[d] = acc;
    }
    __syncthreads();

    // ---- switch = sigmoid([hid|ctx|x] . Wr + b) ----
    float part = 0.f;
    for (int i = tid; i < 3 * H_; i += 256) {
        float xv = (i < H_) ? hs[i] : (i < 2 * H_) ? cs[i - H_] : xs[i - 2 * H_];
        part += xv * Wr[i];
    }
    red[tid] = part; __syncthreads();
    for (int st = 128; st > 0; st >>= 1) {
        if (tid < st) red[tid] += red[tid + st];
        __syncthreads();
    }
    if (tid == 0) sw_out[row] = 1.f / (1.f + expf(-(red[0] + Wrb[0])));

    // ---- gate head (ctx of step 0) ----
    if (t == 0 && tid < NB_) {
        float acc = 0.f;
        for (int d = 0; d < H_; ++d) acc += cs[d] * Wg[tid * H_ + d];
        gate_out[(size_t)row * NB_ + tid] = acc + Wgb[tid];
    }
}

// ---------------- final-step scale + scatter ----------------
__global__ __launch_bounds__(512)
void scale_scatter(float* __restrict__ out, const u16* __restrict__ pb,
                   const float* __restrict__ rowsum, const float* __restrict__ sw,
                   const float* __restrict__ prob, const int* __restrict__ story,
                   int t) {
    const int row = blockIdx.x;
    const int tid = threadIdx.x;
    float scl = sw[row] / rowsum[t * BS_ + row];
    const u16* ps = pb + (size_t)row * V_;
    float* p = out + ((size_t)row * T_ + t) * V_;
    for (int v = tid * 8; v < V_; v += 512 * 8) {
        short8 in = *reinterpret_cast<const short8*>(ps + v);
        float4 o0, o1;
        o0.x = bf2f((u16)in[0]) * scl; o0.y = bf2f((u16)in[1]) * scl;
        o0.z = bf2f((u16)in[2]) * scl; o0.w = bf2f((u16)in[3]) * scl;
        o1.x = bf2f((u16)in[4]) * scl; o1.y = bf2f((u16)in[5]) * scl;
        o1.z = bf2f((u16)in[6]) * scl; o1.w = bf2f((u16)in[7]) * scl;
        *reinterpret_cast<float4*>(p + v) = o0;
        *reinterpret_cast<float4*>(p + v + 4) = o1;
    }
    __syncthreads();
    const int batch = row % B_;
    float om = 1.f - sw[row];
    for (int s = tid; s < S_; s += 512) {
        int tok = story[batch * S_ + s];
        atomicAdd(p + tok, om * prob[(size_t)row * S_ + s]);
    }
}

extern "C" void kernel_launch(void* const* d_in, const int* in_sizes, int n_in,
                              void* d_out, int out_size, void* d_ws, size_t ws_size,
                              hipStream_t stream) {
    const float* eh    = (const float*)d_in[0];
    const float* enc   = (const float*)d_in[1];
    const int*   story = (const int*)d_in[2];
    const int*   tb    = (const int*)d_in[3];
    const int*   dom   = (const int*)d_in[4];
    const int*   sli   = (const int*)d_in[5];
    const float* embW  = (const float*)d_in[6];
    const float* sembW = (const float*)d_in[7];
    const float* Wih   = (const float*)d_in[8];
    const float* Whh   = (const float*)d_in[9];
    const float* bih   = (const float*)d_in[10];
    const float* bhh   = (const float*)d_in[11];
    const float* Wr    = (const float*)d_in[12];
    const float* Wrb   = (const float*)d_in[13];
    const float* Wg    = (const float*)d_in[14];
    const float* Wgb   = (const float*)d_in[15];

    float* out = (float*)d_out;
    float* ws  = (float*)d_ws;

    float* gx_all = ws;                        // [MA_][1200]
    float* gh     = gx_all + (size_t)MA_ * 3 * H_;
    float* hid    = gh + (size_t)BS_ * 3 * H_; // [480][400]
    float* x_all  = hid + (size_t)BS_ * H_;    // [MA_][400]
    float* prob   = x_all + (size_t)MA_ * H_;  // [480][200]
    float* sw     = prob + BS_ * S_;           // [480]
    float* rowsum = sw + BS_;                  // [T_*BS_]
    u16* Ab     = (u16*)(rowsum + T_ * BS_);   // [MP_][KP_]
    u16* Xb_all = Ab + (size_t)MP_ * KP_;      // [MA_][KP_]
    u16* Wihb   = Xb_all + (size_t)MA_ * KP_;  // [NG_][KP_]
    u16* Whhb   = Wihb + (size_t)NG_ * KP_;    // [NG_][KP_]
    u16* Bb     = Whhb + (size_t)NG_ * KP_;    // [NP_][KP_]
    u16* pb     = Bb + (size_t)NP_ * KP_;      // [BS_][V_]
    size_t need = (size_t)((char*)(pb + (size_t)BS_ * V_) - (char*)ws);
    if (ws_size < need) return;

    float* gate_out = out + (size_t)NS_ * B_ * T_ * V_;

    // ---- setup (recurrence-independent) ----
    zero_misc<<<(MP_ * KP_ / 8 + 255) / 256, 256, 0, stream>>>(Ab, rowsum);
    conv_bf16<<<(NP_ * (KP_ / 8) + 255) / 256, 256, 0, stream>>>(embW, Bb, V_, NP_);
    conv_bf16<<<(NG_ * (KP_ / 8) + 255) / 256, 256, 0, stream>>>(Wih, Wihb, 3 * H_, NG_);
    conv_bf16<<<(NG_ * (KP_ / 8) + 255) / 256, 256, 0, stream>>>(Whh, Whhb, 3 * H_, NG_);
    xall_prep<<<(MA_ * (KP_ / 8) + 255) / 256, 256, 0, stream>>>(tb, embW, sembW, dom, sli,
                                                                 x_all, Xb_all);
    init_state<<<(BS_ * H_ + 255) / 256, 256, 0, stream>>>(eh, hid, Ab);
    // all-steps gx: [3840,1200] = Xb_all @ Wih^T, one well-shaped GEMM
    gemm_f32out<<<dim3(NG_ / 128, MA_ / 128), 256, 0, stream>>>(Xb_all, Wihb, gx_all,
                                                                MA_, 3 * H_, 3 * H_);
    // gh(0) = h0 @ Whh^T
    gemm_f32out<<<dim3(NG_ / 128, MP_ / 128), 256, 0, stream>>>(Ab, Whhb, gh,
                                                                BS_, 3 * H_, 3 * H_);

    dim3 gVocab(NVT_ + NG_ / 128, MP_ / 128);   // 206 x 4: vocab tiles + gh(t+1) tiles

    for (int t = 0; t < T_; ++t) {
        attn_fused<<<BS_, 256, 0, stream>>>(gx_all, gh, bih, bhh, hid, Ab, x_all,
                                            enc, story, Wr, Wrb, Wg, Wgb,
                                            prob, sw, gate_out, out, pb, rowsum, t);
        vocab_gh<<<gVocab, 256, 0, stream>>>(Ab, Bb, Whhb, pb, rowsum, gh, t);
    }
    scale_scatter<<<BS_, 512, 0, stream>>>(out, pb, rowsum, sw, prob, story, T_ - 1);
}

// Round 7
// 846.173 us; speedup vs baseline: 3.7787x; 1.4796x over previous
//
#include <hip/hip_runtime.h>
#include <math.h>

#define B_   16
#define S_   200
#define H_   400
#define V_   25000
#define T_   8
#define NS_  30
#define NB_  3
#define NSW_ 36
#define BS_  480   // NS_*B_

#define KP_  448   // K padded (7 tiles of 64)
#define MP_  512   // M padded (4 tiles of 128)
#define NP_  25088 // vocab N padded (196 tiles of 128)
#define NG_  1280  // gates N padded (10 tiles of 128)
#define MA_  3840  // T_*BS_
#define NVT_ (NP_/128)   // 196 vocab n-tiles
#define PSL_ 200         // psum row stride (196 used)

typedef unsigned short u16;
typedef __attribute__((ext_vector_type(4))) float f32x4;
typedef __attribute__((ext_vector_type(8))) short short8;

__device__ __forceinline__ u16 f2bf(float f) {
    unsigned u = __float_as_uint(f);
    u += 0x7FFFu + ((u >> 16) & 1u);
    return (u16)(u >> 16);
}
__device__ __forceinline__ float bf2f(u16 v) {
    return __uint_as_float(((unsigned)v) << 16);
}
__device__ __forceinline__ float wred_sum(float v) {
    v += __shfl_xor(v, 32); v += __shfl_xor(v, 16); v += __shfl_xor(v, 8);
    v += __shfl_xor(v, 4);  v += __shfl_xor(v, 2);  v += __shfl_xor(v, 1);
    return v;
}
__device__ __forceinline__ float wred_max(float v) {
    v = fmaxf(v, __shfl_xor(v, 32)); v = fmaxf(v, __shfl_xor(v, 16));
    v = fmaxf(v, __shfl_xor(v, 8));  v = fmaxf(v, __shfl_xor(v, 4));
    v = fmaxf(v, __shfl_xor(v, 2));  v = fmaxf(v, __shfl_xor(v, 1));
    return v;
}

__device__ __forceinline__ void gload_lds16(const void* g, void* l) {
    __builtin_amdgcn_global_load_lds(
        (const __attribute__((address_space(1))) void*)g,
        (__attribute__((address_space(3))) void*)l, 16, 0, 0);
}

// 128x128 tile, BK=64, 2x2 waves of 64x64; pre-swizzled global source ->
// linear LDS (global_load_lds) -> XOR-swizzled ds_read_b128 (rule #21 pair).
#define MFMA_SETUP()                                                          \
    const int tid = threadIdx.x;                                              \
    const int wid = tid >> 6, lane = tid & 63;                                \
    const int wr = wid >> 1, wc = wid & 1;                                    \
    f32x4 acc[4][4] = {};                                                     \
    const int sslot = lane & 7;                                               \
    const int srow8 = (lane >> 3) & 7;                                        \
    const int lcol = (sslot ^ srow8) * 8;                                     \
    const int lr = lane & 15, lg = lane >> 4, lx = lane & 7;                  \
    const int sA0 = (lg ^ lx) * 8, sA1 = ((4 + lg) ^ lx) * 8;

#define STAGE_TILE(As_, Bs_, k0_)                                             \
    {                                                                         \
        _Pragma("unroll")                                                     \
        for (int is = 0; is < 4; ++is) {                                      \
            gload_lds16(Ag + (size_t)is * 8 * KP_ + (k0_),                    \
                        &(As_)[(wid * 32 + is * 8) * 64]);                    \
            gload_lds16(Bg + (size_t)is * 8 * KP_ + (k0_),                    \
                        &(Bs_)[(wid * 32 + is * 8) * 64]);                    \
        }                                                                     \
    }

#define COMPUTE_TILE(As_, Bs_)                                                \
    {                                                                         \
        short8 af[4][2], bfr[4][2];                                           \
        _Pragma("unroll")                                                     \
        for (int i = 0; i < 4; ++i) {                                         \
            int ra = (wr * 64 + i * 16 + lr) * 64;                            \
            af[i][0] = *reinterpret_cast<const short8*>(&(As_)[ra + sA0]);    \
            af[i][1] = *reinterpret_cast<const short8*>(&(As_)[ra + sA1]);    \
            int rb = (wc * 64 + i * 16 + lr) * 64;                            \
            bfr[i][0] = *reinterpret_cast<const short8*>(&(Bs_)[rb + sA0]);   \
            bfr[i][1] = *reinterpret_cast<const short8*>(&(Bs_)[rb + sA1]);   \
        }                                                                     \
        _Pragma("unroll")                                                     \
        for (int h = 0; h < 2; ++h)                                           \
            _Pragma("unroll")                                                 \
            for (int i = 0; i < 4; ++i)                                       \
                _Pragma("unroll")                                             \
                for (int j = 0; j < 4; ++j)                                   \
                    acc[i][j] = __builtin_amdgcn_mfma_f32_16x16x32_bf16(      \
                        af[i][h], bfr[j][h], acc[i][j], 0, 0, 0);             \
    }

#define MFMA_KLOOP()                                                          \
    STAGE_TILE(As[0], Bs[0], 0);                                              \
    __syncthreads();                                                          \
    _Pragma("unroll")                                                         \
    for (int kt = 0; kt < 6; ++kt) {                                          \
        const int cur = kt & 1, nxt = cur ^ 1;                                \
        STAGE_TILE(As[nxt], Bs[nxt], (kt + 1) * 64);                          \
        COMPUTE_TILE(As[cur], Bs[cur]);                                       \
        __syncthreads();                                                      \
    }                                                                         \
    COMPUTE_TILE(As[0], Bs[0]);

// ---------------- zero Ab (pads persist; live rows rewritten every step) ----------------
__global__ void zero_ab(u16* __restrict__ Ab) {
    int i = blockIdx.x * blockDim.x + threadIdx.x;
    if (i < MP_ * KP_ / 8) {
        short8 z = {};
        *reinterpret_cast<short8*>(Ab + (size_t)i * 8) = z;
    }
}

// ---------------- fp32[rows][400] -> bf16[prows][448] ----------------
__global__ void conv_bf16(const float* __restrict__ src, u16* __restrict__ dst,
                          int rows, int prows) {
    int i = blockIdx.x * blockDim.x + threadIdx.x;
    if (i >= prows * (KP_ / 8)) return;
    int row = i / (KP_ / 8), c8 = (i - row * (KP_ / 8)) * 8;
    short8 o = {};
    if (row < rows && c8 < H_) {
        const float4* s = reinterpret_cast<const float4*>(src + (size_t)row * H_ + c8);
        float4 a = s[0], b = s[1];
        o[0] = (short)f2bf(a.x); o[1] = (short)f2bf(a.y);
        o[2] = (short)f2bf(a.z); o[3] = (short)f2bf(a.w);
        o[4] = (short)f2bf(b.x); o[5] = (short)f2bf(b.y);
        o[6] = (short)f2bf(b.z); o[7] = (short)f2bf(b.w);
    }
    *reinterpret_cast<short8*>(dst + (size_t)row * KP_ + c8) = o;
}

// ---------------- all-steps teacher-forcing inputs ----------------
__global__ void xall_prep(const int* __restrict__ tb, const float* __restrict__ embW,
                          const float* __restrict__ sembW,
                          const int* __restrict__ dom, const int* __restrict__ sli,
                          float* __restrict__ x_all, u16* __restrict__ Xb_all) {
    int i = blockIdx.x * blockDim.x + threadIdx.x;
    if (i >= MA_ * (KP_ / 8)) return;
    int row = i / (KP_ / 8), c8 = (i - row * (KP_ / 8)) * 8;
    int t = row / BS_, r = row - t * BS_;
    int batch = r % B_, slot = r / B_;
    short8 o = {};
    if (c8 < H_) {
        float4 a, b;
        if (t == 0) {
            const float4* s0 = reinterpret_cast<const float4*>(sembW + dom[slot] * H_ + c8);
            const float4* s1 = reinterpret_cast<const float4*>(sembW + sli[slot] * H_ + c8);
            float4 x0 = s0[0], x1 = s0[1], y0 = s1[0], y1 = s1[1];
            a = make_float4(x0.x + y0.x, x0.y + y0.y, x0.z + y0.z, x0.w + y0.w);
            b = make_float4(x1.x + y1.x, x1.y + y1.y, x1.z + y1.z, x1.w + y1.w);
        } else {
            int tok = tb[(batch * NS_ + slot) * T_ + (t - 1)];
            const float4* s = reinterpret_cast<const float4*>(embW + (size_t)tok * H_ + c8);
            a = s[0]; b = s[1];
        }
        o[0] = (short)f2bf(a.x); o[1] = (short)f2bf(a.y);
        o[2] = (short)f2bf(a.z); o[3] = (short)f2bf(a.w);
        o[4] = (short)f2bf(b.x); o[5] = (short)f2bf(b.y);
        o[6] = (short)f2bf(b.z); o[7] = (short)f2bf(b.w);
        *reinterpret_cast<float4*>(x_all + (size_t)row * H_ + c8) = a;
        *reinterpret_cast<float4*>(x_all + (size_t)row * H_ + c8 + 4) = b;
    }
    *reinterpret_cast<short8*>(Xb_all + (size_t)row * KP_ + c8) = o;
}

// ---------------- init: h0 fp32 + bf16 ----------------
__global__ void init_state(const float* __restrict__ eh, float* __restrict__ hid,
                           u16* __restrict__ Ab) {
    int i = blockIdx.x * blockDim.x + threadIdx.x;
    if (i >= BS_ * H_) return;
    int row = i / H_, d = i - row * H_;
    int batch = row % B_;
    float h = eh[batch * H_ + d];
    hid[i] = h;
    Ab[(size_t)row * KP_ + d] = f2bf(h);
}

// ---------------- generic bf16 MFMA GEMM, fp32 out ----------------
__global__ __launch_bounds__(256)
void gemm_f32out(const u16* __restrict__ A, const u16* __restrict__ Bw,
                 float* __restrict__ C, int Mlim, int Nlim, int ldc) {
    __shared__ u16 As[2][128 * 64];
    __shared__ u16 Bs[2][128 * 64];
    const int m0 = blockIdx.y * 128, n0 = blockIdx.x * 128;
    MFMA_SETUP();
    const u16* Ag = A + (size_t)(m0 + wid * 32 + (lane >> 3)) * KP_ + lcol;
    const u16* Bg = Bw + (size_t)(n0 + wid * 32 + (lane >> 3)) * KP_ + lcol;
    MFMA_KLOOP();
    const int m_base = m0 + wr * 64 + lg * 4;
    const int n_base = n0 + wc * 64 + lr;
    #pragma unroll
    for (int i = 0; i < 4; ++i)
        #pragma unroll
        for (int r = 0; r < 4; ++r) {
            int m = m_base + i * 16 + r;
            if (m >= Mlim) continue;
            #pragma unroll
            for (int j = 0; j < 4; ++j) {
                int n = n_base + j * 16;
                if (n < Nlim) C[(size_t)m * ldc + n] = acc[i][j][r];
            }
        }
}

// ---------------- vocab MFMA (exp->pb + psum partials) fused with gh(t+1) GEMM ----------------
// Grid: 824 blocks, XCD-swizzled so the 4 m-tiles of one n-tile are adjacent.
__global__ __launch_bounds__(256)
void vocab_gh(const u16* __restrict__ A, const u16* __restrict__ Bb,
              const u16* __restrict__ Whhb, u16* __restrict__ pb,
              float* __restrict__ psum, float* __restrict__ gh) {
    __shared__ u16 As[2][128 * 64];
    __shared__ u16 Bs[2][128 * 64];
    __shared__ float sred[2][128];
    const int bid = blockIdx.x;                     // 824 = 8*103
    const int lin = (bid & 7) * 103 + (bid >> 3);   // bijective
    const int ntall = lin >> 2, mt = lin & 3;
    const bool isv = (ntall < NVT_);
    const int n0 = (isv ? ntall : ntall - NVT_) * 128;
    const int m0 = mt * 128;
    const u16* Bsrc = isv ? Bb : Whhb;

    MFMA_SETUP();
    const u16* Ag = A + (size_t)(m0 + wid * 32 + (lane >> 3)) * KP_ + lcol;
    const u16* Bg = Bsrc + (size_t)(n0 + wid * 32 + (lane >> 3)) * KP_ + lcol;
    MFMA_KLOOP();

    const int m_base = m0 + wr * 64 + lg * 4;
    const int n_base = n0 + wc * 64 + lr;
    if (isv) {
        #pragma unroll
        for (int i = 0; i < 4; ++i) {
            #pragma unroll
            for (int r = 0; r < 4; ++r) {
                int m = m_base + i * 16 + r;
                float js = 0.f;
                #pragma unroll
                for (int j = 0; j < 4; ++j) {
                    int n = n_base + j * 16;
                    float e = __expf(acc[i][j][r]);
                    if (m < BS_ && n < V_) {
                        pb[(size_t)m * V_ + n] = f2bf(e);
                        js += e;
                    }
                }
                js += __shfl_xor(js, 1);
                js += __shfl_xor(js, 2);
                js += __shfl_xor(js, 4);
                js += __shfl_xor(js, 8);
                if ((lane & 15) == 0) sred[wc][m - m0] = js;
            }
        }
        __syncthreads();
        if (tid < 128) {
            int m = m0 + tid;
            psum[(size_t)m * PSL_ + ntall] = sred[0][tid] + sred[1][tid];
        }
    } else {
        #pragma unroll
        for (int i = 0; i < 4; ++i)
            #pragma unroll
            for (int r = 0; r < 4; ++r) {
                int m = m_base + i * 16 + r;
                if (m >= BS_) continue;
                #pragma unroll
                for (int j = 0; j < 4; ++j) {
                    int n = n_base + j * 16;
                    if (n < 3 * H_) gh[(size_t)m * 3 * H_ + n] = acc[i][j][r];
                }
            }
    }
}

// ---------------- fused: [finalize step t-1] + GRU + attention + switch ----------------
// Grid 480, XCD-swizzled so same-batch rows (shared enc slice) group per XCD.
__global__ __launch_bounds__(256)
void attn_fused(const float* __restrict__ gx_all, const float* __restrict__ gh,
                const float* __restrict__ bih, const float* __restrict__ bhh,
                float* __restrict__ hid, u16* __restrict__ Ab,
                const float* __restrict__ x_all,
                const float* __restrict__ enc, const int* __restrict__ story,
                const float* __restrict__ Wr, const float* __restrict__ Wrb,
                const float* __restrict__ Wg, const float* __restrict__ Wgb,
                float* __restrict__ prob, float* __restrict__ sw_out,
                float* __restrict__ gate_out,
                float* __restrict__ out, const u16* __restrict__ pb,
                const float* __restrict__ psum, int t) {
    const int bid = blockIdx.x;                    // 480 = 8*60
    const int lin = (bid & 7) * 60 + (bid >> 3);
    const int batch = lin / 30, slot = lin - batch * 30;
    const int row = slot * B_ + batch;
    const int tid = threadIdx.x, w = tid >> 6, l = tid & 63;
    __shared__ __align__(16) float hs[H_];
    __shared__ __align__(16) float xs[H_];
    __shared__ __align__(16) float cs[H_];
    __shared__ float sc[S_];
    __shared__ float red[16];

    // ---- finalize step t-1 for this row: denom from psum, scale pb->out, scatter ----
    if (t > 0) {
        float rs = (tid < NVT_) ? psum[(size_t)row * PSL_ + tid] : 0.f;
        rs = wred_sum(rs);
        if (l == 0) red[w] = rs;
        __syncthreads();
        float denom = red[0] + red[1] + red[2] + red[3];
        float swv = sw_out[row];
        float scl = swv / denom;
        const u16* ps = pb + (size_t)row * V_;
        float* p = out + ((size_t)row * T_ + (t - 1)) * V_;
        for (int v = tid * 8; v < V_; v += 256 * 8) {
            short8 in = *reinterpret_cast<const short8*>(ps + v);
            float4 o0, o1;
            o0.x = bf2f((u16)in[0]) * scl; o0.y = bf2f((u16)in[1]) * scl;
            o0.z = bf2f((u16)in[2]) * scl; o0.w = bf2f((u16)in[3]) * scl;
            o1.x = bf2f((u16)in[4]) * scl; o1.y = bf2f((u16)in[5]) * scl;
            o1.z = bf2f((u16)in[6]) * scl; o1.w = bf2f((u16)in[7]) * scl;
            *reinterpret_cast<float4*>(p + v) = o0;
            *reinterpret_cast<float4*>(p + v + 4) = o1;
        }
        __syncthreads();
        float om = 1.f - swv;
        for (int s = tid; s < S_; s += 256) {
            int tok = story[batch * S_ + s];
            atomicAdd(p + tok, om * prob[(size_t)row * S_ + s]);
        }
    }

    // ---- GRU cell -> hs (+ hid, bf16 Ab) ----
    const float* gxr = gx_all + ((size_t)t * BS_ + row) * 3 * H_;
    const float* ghr = gh + (size_t)row * 3 * H_;
    const float* xr  = x_all + ((size_t)t * BS_ + row) * H_;
    for (int d = tid; d < H_; d += 256) {
        float r = 1.f / (1.f + expf(-(gxr[d] + bih[d] + ghr[d] + bhh[d])));
        float z = 1.f / (1.f + expf(-(gxr[H_ + d] + bih[H_ + d] + ghr[H_ + d] + bhh[H_ + d])));
        float n = tanhf(gxr[2 * H_ + d] + bih[2 * H_ + d] + r * (ghr[2 * H_ + d] + bhh[2 * H_ + d]));
        float h = (1.f - z) * n + z * hid[(size_t)row * H_ + d];
        hs[d] = h;
        hid[(size_t)row * H_ + d] = h;
        Ab[(size_t)row * KP_ + d] = f2bf(h);
        xs[d] = xr[d];
    }
    __syncthreads();

    // ---- scores, wave-cooperative (coalesced): wave w owns s in [w*50, w*50+50) ----
    const float* encb = enc + (size_t)batch * S_ * H_;
    {
        float4 hv1 = *reinterpret_cast<const float4*>(&hs[l * 4]);
        float4 hv2 = make_float4(0.f, 0.f, 0.f, 0.f);
        if (l < 36) hv2 = *reinterpret_cast<const float4*>(&hs[256 + l * 4]);
        for (int k = 0; k < 50; ++k) {
            int s = w * 50 + k;
            const float4* e = reinterpret_cast<const float4*>(encb + (size_t)s * H_);
            float4 ev = e[l];
            float part = ev.x * hv1.x + ev.y * hv1.y + ev.z * hv1.z + ev.w * hv1.w;
            if (l < 36) {
                float4 ev2 = e[64 + l];
                part += ev2.x * hv2.x + ev2.y * hv2.y + ev2.z * hv2.z + ev2.w * hv2.w;
            }
            part = wred_sum(part);
            if (l == 0)
                sc[s] = (story[batch * S_ + s] == 0) ? -1e30f : part;
        }
    }
    __syncthreads();

    // ---- softmax over S_=200 (wave reduce + 1 LDS combine) ----
    float v = (tid < S_) ? sc[tid] : -1e30f;
    float wm = wred_max(v);
    if (l == 0) red[w] = wm;
    __syncthreads();
    float mx = fmaxf(fmaxf(red[0], red[1]), fmaxf(red[2], red[3]));
    float e = (tid < S_) ? __expf(v - mx) : 0.f;
    float wsum = wred_sum(e);
    if (l == 0) red[4 + w] = wsum;
    __syncthreads();
    float inv = 1.f / (red[4] + red[5] + red[6] + red[7]);
    if (tid < S_) {
        float pv = e * inv;
        sc[tid] = pv;
        prob[(size_t)row * S_ + tid] = pv;
    }
    __syncthreads();

    // ---- ctx (coalesced over d, 2 accumulators) ----
    for (int d = tid; d < H_; d += 256) {
        float a0 = 0.f, a1 = 0.f;
        for (int s = 0; s < S_; s += 2) {
            a0 += sc[s] * encb[(size_t)s * H_ + d];
            a1 += sc[s + 1] * encb[(size_t)(s + 1) * H_ + d];
        }
        cs[d] = a0 + a1;
    }
    __syncthreads();

    // ---- switch = sigmoid([hid|ctx|x] . Wr + b) ----
    float part = 0.f;
    for (int i = tid; i < 3 * H_; i += 256) {
        float xv = (i < H_) ? hs[i] : (i < 2 * H_) ? cs[i - H_] : xs[i - 2 * H_];
        part += xv * Wr[i];
    }
    part = wred_sum(part);
    if (l == 0) red[8 + w] = part;
    __syncthreads();
    if (tid == 0)
        sw_out[row] = 1.f / (1.f + expf(-(red[8] + red[9] + red[10] + red[11] + Wrb[0])));

    // ---- gate head (ctx of step 0) ----
    if (t == 0 && tid < NB_) {
        float acc = 0.f;
        for (int d = 0; d < H_; ++d) acc += cs[d] * Wg[tid * H_ + d];
        gate_out[(size_t)row * NB_ + tid] = acc + Wgb[tid];
    }
}

// ---------------- final-step finalize ----------------
__global__ __launch_bounds__(256)
void scale_scatter(float* __restrict__ out, const u16* __restrict__ pb,
                   const float* __restrict__ psum, const float* __restrict__ sw,
                   const float* __restrict__ prob, const int* __restrict__ story) {
    const int row = blockIdx.x;
    const int tid = threadIdx.x, w = tid >> 6, l = tid & 63;
    __shared__ float red[4];
    float rs = (tid < NVT_) ? psum[(size_t)row * PSL_ + tid] : 0.f;
    rs = wred_sum(rs);
    if (l == 0) red[w] = rs;
    __syncthreads();
    float denom = red[0] + red[1] + red[2] + red[3];
    float swv = sw[row];
    float scl = swv / denom;
    const u16* ps = pb + (size_t)row * V_;
    float* p = out + ((size_t)row * T_ + (T_ - 1)) * V_;
    for (int v = tid * 8; v < V_; v += 256 * 8) {
        short8 in = *reinterpret_cast<const short8*>(ps + v);
        float4 o0, o1;
        o0.x = bf2f((u16)in[0]) * scl; o0.y = bf2f((u16)in[1]) * scl;
        o0.z = bf2f((u16)in[2]) * scl; o0.w = bf2f((u16)in[3]) * scl;
        o1.x = bf2f((u16)in[4]) * scl; o1.y = bf2f((u16)in[5]) * scl;
        o1.z = bf2f((u16)in[6]) * scl; o1.w = bf2f((u16)in[7]) * scl;
        *reinterpret_cast<float4*>(p + v) = o0;
        *reinterpret_cast<float4*>(p + v + 4) = o1;
    }
    __syncthreads();
    const int batch = row % B_;
    float om = 1.f - swv;
    for (int s = tid; s < S_; s += 256) {
        int tok = story[batch * S_ + s];
        atomicAdd(p + tok, om * prob[(size_t)row * S_ + s]);
    }
}

extern "C" void kernel_launch(void* const* d_in, const int* in_sizes, int n_in,
                              void* d_out, int out_size, void* d_ws, size_t ws_size,
                              hipStream_t stream) {
    const float* eh    = (const float*)d_in[0];
    const float* enc   = (const float*)d_in[1];
    const int*   story = (const int*)d_in[2];
    const int*   tb    = (const int*)d_in[3];
    const int*   dom   = (const int*)d_in[4];
    const int*   sli   = (const int*)d_in[5];
    const float* embW  = (const float*)d_in[6];
    const float* sembW = (const float*)d_in[7];
    const float* Wih   = (const float*)d_in[8];
    const float* Whh   = (const float*)d_in[9];
    const float* bih   = (const float*)d_in[10];
    const float* bhh   = (const float*)d_in[11];
    const float* Wr    = (const float*)d_in[12];
    const float* Wrb   = (const float*)d_in[13];
    const float* Wg    = (const float*)d_in[14];
    const float* Wgb   = (const float*)d_in[15];

    float* out = (float*)d_out;
    float* ws  = (float*)d_ws;

    float* gx_all = ws;                        // [MA_][1200]
    float* gh     = gx_all + (size_t)MA_ * 3 * H_;
    float* hid    = gh + (size_t)BS_ * 3 * H_; // [480][400]
    float* x_all  = hid + (size_t)BS_ * H_;    // [MA_][400]
    float* prob   = x_all + (size_t)MA_ * H_;  // [480][200]
    float* sw     = prob + BS_ * S_;           // [480]
    float* psum   = sw + BS_;                  // [MP_][PSL_]
    u16* Ab     = (u16*)(psum + (size_t)MP_ * PSL_);  // [MP_][KP_]
    u16* Xb_all = Ab + (size_t)MP_ * KP_;      // [MA_][KP_]
    u16* Wihb   = Xb_all + (size_t)MA_ * KP_;  // [NG_][KP_]
    u16* Whhb   = Wihb + (size_t)NG_ * KP_;    // [NG_][KP_]
    u16* Bb     = Whhb + (size_t)NG_ * KP_;    // [NP_][KP_]
    u16* pb     = Bb + (size_t)NP_ * KP_;      // [BS_][V_]
    size_t need = (size_t)((char*)(pb + (size_t)BS_ * V_) - (char*)ws);
    if (ws_size < need) return;

    float* gate_out = out + (size_t)NS_ * B_ * T_ * V_;

    // ---- setup (recurrence-independent) ----
    zero_ab<<<(MP_ * KP_ / 8 + 255) / 256, 256, 0, stream>>>(Ab);
    conv_bf16<<<(NP_ * (KP_ / 8) + 255) / 256, 256, 0, stream>>>(embW, Bb, V_, NP_);
    conv_bf16<<<(NG_ * (KP_ / 8) + 255) / 256, 256, 0, stream>>>(Wih, Wihb, 3 * H_, NG_);
    conv_bf16<<<(NG_ * (KP_ / 8) + 255) / 256, 256, 0, stream>>>(Whh, Whhb, 3 * H_, NG_);
    xall_prep<<<(MA_ * (KP_ / 8) + 255) / 256, 256, 0, stream>>>(tb, embW, sembW, dom, sli,
                                                                 x_all, Xb_all);
    init_state<<<(BS_ * H_ + 255) / 256, 256, 0, stream>>>(eh, hid, Ab);
    gemm_f32out<<<dim3(NG_ / 128, MA_ / 128), 256, 0, stream>>>(Xb_all, Wihb, gx_all,
                                                                MA_, 3 * H_, 3 * H_);
    gemm_f32out<<<dim3(NG_ / 128, MP_ / 128), 256, 0, stream>>>(Ab, Whhb, gh,
                                                                BS_, 3 * H_, 3 * H_);

    for (int t = 0; t < T_; ++t) {
        attn_fused<<<BS_, 256, 0, stream>>>(gx_all, gh, bih, bhh, hid, Ab, x_all,
                                            enc, story, Wr, Wrb, Wg, Wgb,
                                            prob, sw, gate_out, out, pb, psum, t);
        vocab_gh<<<824, 256, 0, stream>>>(Ab, Bb, Whhb, pb, psum, gh);
    }
    scale_scatter<<<BS_, 256, 0, stream>>>(out, pb, psum, sw, prob, story);
}

// Round 9
// 806.996 us; speedup vs baseline: 3.9622x; 1.0485x over previous
//
#include <hip/hip_runtime.h>
#include <math.h>

#define B_   16
#define S_   200
#define H_   400
#define V_   25000
#define T_   8
#define NS_  30
#define NB_  3
#define NSW_ 36
#define BS_  480   // NS_*B_

#define KP_  448   // K padded (7 tiles of 64)
#define MP_  512   // M padded (4 tiles of 128)
#define NP_  25088 // vocab N padded (196 tiles of 128)
#define NG_  1280  // gates N padded (10 tiles of 128)
#define MA_  3840  // T_*BS_
#define NVT_ (NP_/128)   // 196 vocab n-tiles
#define PSL_ 200         // psum row stride (196 used)

typedef unsigned short u16;
typedef __attribute__((ext_vector_type(4))) float f32x4;
typedef __attribute__((ext_vector_type(8))) short short8;

__device__ __forceinline__ u16 f2bf(float f) {
    unsigned u = __float_as_uint(f);
    u += 0x7FFFu + ((u >> 16) & 1u);
    return (u16)(u >> 16);
}
__device__ __forceinline__ float bf2f(u16 v) {
    return __uint_as_float(((unsigned)v) << 16);
}
__device__ __forceinline__ float wred_sum(float v) {
    v += __shfl_xor(v, 32); v += __shfl_xor(v, 16); v += __shfl_xor(v, 8);
    v += __shfl_xor(v, 4);  v += __shfl_xor(v, 2);  v += __shfl_xor(v, 1);
    return v;
}
__device__ __forceinline__ float wred_max(float v) {
    v = fmaxf(v, __shfl_xor(v, 32)); v = fmaxf(v, __shfl_xor(v, 16));
    v = fmaxf(v, __shfl_xor(v, 8));  v = fmaxf(v, __shfl_xor(v, 4));
    v = fmaxf(v, __shfl_xor(v, 2));  v = fmaxf(v, __shfl_xor(v, 1));
    return v;
}

__device__ __forceinline__ void gload_lds16(const void* g, void* l) {
    __builtin_amdgcn_global_load_lds(
        (const __attribute__((address_space(1))) void*)g,
        (__attribute__((address_space(3))) void*)l, 16, 0, 0);
}

// 128x128 tile, BK=64, 2x2 waves of 64x64; pre-swizzled global source ->
// linear LDS (global_load_lds) -> XOR-swizzled ds_read_b128 (rule #21 pair).
// Single-buffered (m97 structure): 32KB LDS -> higher residency.
// NOTE: caller must have `const int tid` in scope before MFMA_SETUP().
#define MFMA_SETUP()                                                          \
    const int wid = tid >> 6, lane = tid & 63;                                \
    const int wr = wid >> 1, wc = wid & 1;                                    \
    f32x4 acc[4][4] = {};                                                     \
    const int sslot = lane & 7;                                               \
    const int srow8 = (lane >> 3) & 7;                                        \
    const int lcol = (sslot ^ srow8) * 8;                                     \
    const int lr = lane & 15, lg = lane >> 4, lx = lane & 7;                  \
    const int sA0 = (lg ^ lx) * 8, sA1 = ((4 + lg) ^ lx) * 8;

#define STAGE_TILE(k0_)                                                       \
    {                                                                         \
        _Pragma("unroll")                                                     \
        for (int is = 0; is < 4; ++is) {                                      \
            gload_lds16(Ag + (size_t)is * 8 * KP_ + (k0_),                    \
                        &As[(wid * 32 + is * 8) * 64]);                       \
            gload_lds16(Bg + (size_t)is * 8 * KP_ + (k0_),                    \
                        &Bs[(wid * 32 + is * 8) * 64]);                       \
        }                                                                     \
    }

#define COMPUTE_TILE()                                                        \
    {                                                                         \
        short8 af[4][2], bfr[4][2];                                           \
        _Pragma("unroll")                                                     \
        for (int i = 0; i < 4; ++i) {                                         \
            int ra = (wr * 64 + i * 16 + lr) * 64;                            \
            af[i][0] = *reinterpret_cast<const short8*>(&As[ra + sA0]);       \
            af[i][1] = *reinterpret_cast<const short8*>(&As[ra + sA1]);       \
            int rb = (wc * 64 + i * 16 + lr) * 64;                            \
            bfr[i][0] = *reinterpret_cast<const short8*>(&Bs[rb + sA0]);      \
            bfr[i][1] = *reinterpret_cast<const short8*>(&Bs[rb + sA1]);      \
        }                                                                     \
        _Pragma("unroll")                                                     \
        for (int h = 0; h < 2; ++h)                                           \
            _Pragma("unroll")                                                 \
            for (int i = 0; i < 4; ++i)                                       \
                _Pragma("unroll")                                             \
                for (int j = 0; j < 4; ++j)                                   \
                    acc[i][j] = __builtin_amdgcn_mfma_f32_16x16x32_bf16(      \
                        af[i][h], bfr[j][h], acc[i][j], 0, 0, 0);             \
    }

#define MFMA_KLOOP_SB()                                                       \
    _Pragma("unroll")                                                         \
    for (int kt = 0; kt < 7; ++kt) {                                          \
        STAGE_TILE(kt * 64);                                                  \
        __syncthreads();                                                      \
        COMPUTE_TILE();                                                       \
        __syncthreads();                                                      \
    }

// ---------------- setup: Ab zero+h0, hid ----------------
__global__ void init_all(const float* __restrict__ eh, float* __restrict__ hid,
                         u16* __restrict__ Ab) {
    int i = blockIdx.x * blockDim.x + threadIdx.x;
    if (i >= MP_ * KP_) return;
    int row = i / KP_, d = i - row * KP_;
    u16 v = 0;
    if (row < BS_ && d < H_) {
        float h = eh[(row % B_) * H_ + d];
        hid[row * H_ + d] = h;
        v = f2bf(h);
    }
    Ab[i] = v;
}

// ---------------- setup: all fp32->bf16 weight conversions in one launch ----------------
__device__ __forceinline__ void conv_chunk(const float* __restrict__ src,
                                           u16* __restrict__ dst, int i, int rows) {
    int row = i / (KP_ / 8), c8 = (i - row * (KP_ / 8)) * 8;
    short8 o = {};
    if (row < rows && c8 < H_) {
        const float4* s = reinterpret_cast<const float4*>(src + (size_t)row * H_ + c8);
        float4 a = s[0], b = s[1];
        o[0] = (short)f2bf(a.x); o[1] = (short)f2bf(a.y);
        o[2] = (short)f2bf(a.z); o[3] = (short)f2bf(a.w);
        o[4] = (short)f2bf(b.x); o[5] = (short)f2bf(b.y);
        o[6] = (short)f2bf(b.z); o[7] = (short)f2bf(b.w);
    }
    *reinterpret_cast<short8*>(dst + (size_t)row * KP_ + c8) = o;
}

__global__ void conv_all(const float* __restrict__ embW, const float* __restrict__ Wih,
                         const float* __restrict__ Whh, u16* __restrict__ Bb,
                         u16* __restrict__ Wihb, u16* __restrict__ Whhb) {
    const int CB = NP_ * (KP_ / 8), CG = NG_ * (KP_ / 8);
    int i = blockIdx.x * blockDim.x + threadIdx.x;
    if (i < CB) conv_chunk(embW, Bb, i, V_);
    else if (i < CB + CG) conv_chunk(Wih, Wihb, i - CB, 3 * H_);
    else if (i < CB + 2 * CG) conv_chunk(Whh, Whhb, i - CB - CG, 3 * H_);
}

// ---------------- all-steps teacher-forcing inputs ----------------
__global__ void xall_prep(const int* __restrict__ tb, const float* __restrict__ embW,
                          const float* __restrict__ sembW,
                          const int* __restrict__ dom, const int* __restrict__ sli,
                          float* __restrict__ x_all, u16* __restrict__ Xb_all) {
    int i = blockIdx.x * blockDim.x + threadIdx.x;
    if (i >= MA_ * (KP_ / 8)) return;
    int row = i / (KP_ / 8), c8 = (i - row * (KP_ / 8)) * 8;
    int t = row / BS_, r = row - t * BS_;
    int batch = r % B_, slot = r / B_;
    short8 o = {};
    if (c8 < H_) {
        float4 a, b;
        if (t == 0) {
            const float4* s0 = reinterpret_cast<const float4*>(sembW + dom[slot] * H_ + c8);
            const float4* s1 = reinterpret_cast<const float4*>(sembW + sli[slot] * H_ + c8);
            float4 x0 = s0[0], x1 = s0[1], y0 = s1[0], y1 = s1[1];
            a = make_float4(x0.x + y0.x, x0.y + y0.y, x0.z + y0.z, x0.w + y0.w);
            b = make_float4(x1.x + y1.x, x1.y + y1.y, x1.z + y1.z, x1.w + y1.w);
        } else {
            int tok = tb[(batch * NS_ + slot) * T_ + (t - 1)];
            const float4* s = reinterpret_cast<const float4*>(embW + (size_t)tok * H_ + c8);
            a = s[0]; b = s[1];
        }
        o[0] = (short)f2bf(a.x); o[1] = (short)f2bf(a.y);
        o[2] = (short)f2bf(a.z); o[3] = (short)f2bf(a.w);
        o[4] = (short)f2bf(b.x); o[5] = (short)f2bf(b.y);
        o[6] = (short)f2bf(b.z); o[7] = (short)f2bf(b.w);
        *reinterpret_cast<float4*>(x_all + (size_t)row * H_ + c8) = a;
        *reinterpret_cast<float4*>(x_all + (size_t)row * H_ + c8 + 4) = b;
    }
    *reinterpret_cast<short8*>(Xb_all + (size_t)row * KP_ + c8) = o;
}

// ---------------- setup GEMMs combined: gx_all (y<30) + gh(0) (y>=30) ----------------
__global__ __launch_bounds__(256)
void gemm_setup(const u16* __restrict__ Xb_all, const u16* __restrict__ Abuf,
                const u16* __restrict__ Wihb, const u16* __restrict__ Whhb,
                float* __restrict__ gx_all, float* __restrict__ gh) {
    __shared__ u16 As[128 * 64];
    __shared__ u16 Bs[128 * 64];
    const int tid = threadIdx.x;
    const bool mainp = blockIdx.y < (MA_ / 128);
    const int m0 = (mainp ? blockIdx.y : blockIdx.y - MA_ / 128) * 128;
    const int n0 = blockIdx.x * 128;
    const u16* A = mainp ? Xb_all : Abuf;
    const u16* Bw = mainp ? Wihb : Whhb;
    float* C = mainp ? gx_all : gh;
    const int Mlim = mainp ? MA_ : BS_;

    MFMA_SETUP();
    const u16* Ag = A + (size_t)(m0 + wid * 32 + (lane >> 3)) * KP_ + lcol;
    const u16* Bg = Bw + (size_t)(n0 + wid * 32 + (lane >> 3)) * KP_ + lcol;
    MFMA_KLOOP_SB();

    const int m_base = m0 + wr * 64 + lg * 4;
    const int n_base = n0 + wc * 64 + lr;
    #pragma unroll
    for (int i = 0; i < 4; ++i)
        #pragma unroll
        for (int r = 0; r < 4; ++r) {
            int m = m_base + i * 16 + r;
            if (m >= Mlim) continue;
            #pragma unroll
            for (int j = 0; j < 4; ++j) {
                int n = n_base + j * 16;
                if (n < 3 * H_) C[(size_t)m * 3 * H_ + n] = acc[i][j][r];
            }
        }
}

// ---------------- vocab MFMA (exp->pb + psum) + gh(t+1) tiles + optional finalize(t-1) ----------------
__global__ __launch_bounds__(256)
void vocab_gh(const u16* __restrict__ A, const u16* __restrict__ Bb,
              const u16* __restrict__ Whhb, u16* __restrict__ pb_cur,
              float* __restrict__ psum_cur, float* __restrict__ gh,
              const u16* __restrict__ pb_prev, const float* __restrict__ psum_prev,
              const float* __restrict__ sw_prev, const float* __restrict__ prob_prev,
              const int* __restrict__ story, float* __restrict__ out,
              int t, int do_fin) {
    __shared__ u16 As[128 * 64];
    __shared__ u16 Bs[128 * 64];
    __shared__ float sred[2][128];
    const int bid = blockIdx.x;                     // 824 = 8*103
    const int tid = threadIdx.x;

    // ---- preamble: finalize row `bid` of step t-1 (overlaps other blocks' MFMA) ----
    if (do_fin && t > 0 && bid < BS_) {
        const int row = bid, batch = row % B_;
        const int w = tid >> 6, l = tid & 63;
        float rs = (tid < NVT_) ? psum_prev[(size_t)row * PSL_ + tid] : 0.f;
        rs = wred_sum(rs);
        if (l == 0) sred[0][w] = rs;
        __syncthreads();
        float denom = sred[0][0] + sred[0][1] + sred[0][2] + sred[0][3];
        float swv = sw_prev[row];
        float scl = swv / denom;
        const u16* ps = pb_prev + (size_t)row * V_;
        float* p = out + ((size_t)row * T_ + (t - 1)) * V_;
        for (int v = tid * 8; v < V_; v += 256 * 8) {
            short8 in = *reinterpret_cast<const short8*>(ps + v);
            float4 o0, o1;
            o0.x = bf2f((u16)in[0]) * scl; o0.y = bf2f((u16)in[1]) * scl;
            o0.z = bf2f((u16)in[2]) * scl; o0.w = bf2f((u16)in[3]) * scl;
            o1.x = bf2f((u16)in[4]) * scl; o1.y = bf2f((u16)in[5]) * scl;
            o1.z = bf2f((u16)in[6]) * scl; o1.w = bf2f((u16)in[7]) * scl;
            *reinterpret_cast<float4*>(p + v) = o0;
            *reinterpret_cast<float4*>(p + v + 4) = o1;
        }
        __syncthreads();
        float om = 1.f - swv;
        for (int s = tid; s < S_; s += 256) {
            int tok = story[batch * S_ + s];
            atomicAdd(p + tok, om * prob_prev[(size_t)row * S_ + s]);
        }
        __syncthreads();
    }

    // ---- tile select (XCD-swizzled so 4 m-tiles of one n-tile are adjacent) ----
    const int lin = (bid & 7) * 103 + (bid >> 3);   // bijective
    const int ntall = lin >> 2, mt = lin & 3;
    const bool isv = (ntall < NVT_);
    const int n0 = (isv ? ntall : ntall - NVT_) * 128;
    const int m0 = mt * 128;
    const u16* Bsrc = isv ? Bb : Whhb;

    MFMA_SETUP();
    const u16* Ag = A + (size_t)(m0 + wid * 32 + (lane >> 3)) * KP_ + lcol;
    const u16* Bg = Bsrc + (size_t)(n0 + wid * 32 + (lane >> 3)) * KP_ + lcol;
    MFMA_KLOOP_SB();

    const int m_base = m0 + wr * 64 + lg * 4;
    const int n_base = n0 + wc * 64 + lr;
    if (isv) {
        #pragma unroll
        for (int i = 0; i < 4; ++i) {
            #pragma unroll
            for (int r = 0; r < 4; ++r) {
                int m = m_base + i * 16 + r;
                float js = 0.f;
                #pragma unroll
                for (int j = 0; j < 4; ++j) {
                    int n = n_base + j * 16;
                    float e = __expf(acc[i][j][r]);
                    if (m < BS_ && n < V_) {
                        pb_cur[(size_t)m * V_ + n] = f2bf(e);
                        js += e;
                    }
                }
                js += __shfl_xor(js, 1);
                js += __shfl_xor(js, 2);
                js += __shfl_xor(js, 4);
                js += __shfl_xor(js, 8);
                if ((lane & 15) == 0) sred[wc][m - m0] = js;
            }
        }
        __syncthreads();
        if (tid < 128) {
            int m = m0 + tid;
            psum_cur[(size_t)m * PSL_ + ntall] = sred[0][tid] + sred[1][tid];
        }
    } else {
        #pragma unroll
        for (int i = 0; i < 4; ++i)
            #pragma unroll
            for (int r = 0; r < 4; ++r) {
                int m = m_base + i * 16 + r;
                if (m >= BS_) continue;
                #pragma unroll
                for (int j = 0; j < 4; ++j) {
                    int n = n_base + j * 16;
                    if (n < 3 * H_) gh[(size_t)m * 3 * H_ + n] = acc[i][j][r];
                }
            }
    }
}

// ---------------- fused GRU + attention + switch (+finalize fallback) ----------------
__global__ __launch_bounds__(256)
void attn_fused(const float* __restrict__ gx_all, const float* __restrict__ gh,
                const float* __restrict__ bih, const float* __restrict__ bhh,
                float* __restrict__ hid, u16* __restrict__ Ab,
                const float* __restrict__ x_all,
                const float* __restrict__ enc, const int* __restrict__ story,
                const float* __restrict__ Wr, const float* __restrict__ Wrb,
                const float* __restrict__ Wg, const float* __restrict__ Wgb,
                float* __restrict__ prob_cur, float* __restrict__ sw_cur,
                float* __restrict__ gate_out,
                float* __restrict__ out, const u16* __restrict__ pb_prev,
                const float* __restrict__ psum_prev, const float* __restrict__ sw_prev,
                const float* __restrict__ prob_prev, int t, int do_fin) {
    const int bid = blockIdx.x;                    // 480 = 8*60
    const int lin = (bid & 7) * 60 + (bid >> 3);
    const int batch = lin / 30, slot = lin - batch * 30;
    const int row = slot * B_ + batch;
    const int tid = threadIdx.x, w = tid >> 6, l = tid & 63;
    __shared__ __align__(16) float hs[H_];
    __shared__ __align__(16) float xs[H_];
    __shared__ __align__(16) float cs[H_];
    __shared__ float sc[S_];
    __shared__ float red[16];

    // ---- fallback finalize (only when pb can't ping-pong) ----
    if (do_fin && t > 0) {
        float rs = (tid < NVT_) ? psum_prev[(size_t)row * PSL_ + tid] : 0.f;
        rs = wred_sum(rs);
        if (l == 0) red[w] = rs;
        __syncthreads();
        float denom = red[0] + red[1] + red[2] + red[3];
        float swv = sw_prev[row];
        float scl = swv / denom;
        const u16* ps = pb_prev + (size_t)row * V_;
        float* p = out + ((size_t)row * T_ + (t - 1)) * V_;
        for (int v = tid * 8; v < V_; v += 256 * 8) {
            short8 in = *reinterpret_cast<const short8*>(ps + v);
            float4 o0, o1;
            o0.x = bf2f((u16)in[0]) * scl; o0.y = bf2f((u16)in[1]) * scl;
            o0.z = bf2f((u16)in[2]) * scl; o0.w = bf2f((u16)in[3]) * scl;
            o1.x = bf2f((u16)in[4]) * scl; o1.y = bf2f((u16)in[5]) * scl;
            o1.z = bf2f((u16)in[6]) * scl; o1.w = bf2f((u16)in[7]) * scl;
            *reinterpret_cast<float4*>(p + v) = o0;
            *reinterpret_cast<float4*>(p + v + 4) = o1;
        }
        __syncthreads();
        float om = 1.f - swv;
        for (int s = tid; s < S_; s += 256) {
            int tok = story[batch * S_ + s];
            atomicAdd(p + tok, om * prob_prev[(size_t)row * S_ + s]);
        }
        __syncthreads();
    }

    // ---- GRU cell -> hs (+ hid, bf16 Ab) ----
    const float* gxr = gx_all + ((size_t)t * BS_ + row) * 3 * H_;
    const float* ghr = gh + (size_t)row * 3 * H_;
    const float* xr  = x_all + ((size_t)t * BS_ + row) * H_;
    for (int d = tid; d < H_; d += 256) {
        float r = 1.f / (1.f + expf(-(gxr[d] + bih[d] + ghr[d] + bhh[d])));
        float z = 1.f / (1.f + expf(-(gxr[H_ + d] + bih[H_ + d] + ghr[H_ + d] + bhh[H_ + d])));
        float n = tanhf(gxr[2 * H_ + d] + bih[2 * H_ + d] + r * (ghr[2 * H_ + d] + bhh[2 * H_ + d]));
        float h = (1.f - z) * n + z * hid[(size_t)row * H_ + d];
        hs[d] = h;
        hid[(size_t)row * H_ + d] = h;
        Ab[(size_t)row * KP_ + d] = f2bf(h);
        xs[d] = xr[d];
    }
    __syncthreads();

    // ---- scores, wave-cooperative (coalesced): wave w owns s in [w*50, w*50+50) ----
    const float* encb = enc + (size_t)batch * S_ * H_;
    {
        float4 hv1 = *reinterpret_cast<const float4*>(&hs[l * 4]);
        float4 hv2 = make_float4(0.f, 0.f, 0.f, 0.f);
        if (l < 36) hv2 = *reinterpret_cast<const float4*>(&hs[256 + l * 4]);
        for (int k = 0; k < 50; ++k) {
            int s = w * 50 + k;
            const float4* e = reinterpret_cast<const float4*>(encb + (size_t)s * H_);
            float4 ev = e[l];
            float part = ev.x * hv1.x + ev.y * hv1.y + ev.z * hv1.z + ev.w * hv1.w;
            if (l < 36) {
                float4 ev2 = e[64 + l];
                part += ev2.x * hv2.x + ev2.y * hv2.y + ev2.z * hv2.z + ev2.w * hv2.w;
            }
            part = wred_sum(part);
            if (l == 0)
                sc[s] = (story[batch * S_ + s] == 0) ? -1e30f : part;
        }
    }
    __syncthreads();

    // ---- softmax over S_=200 ----
    float v = (tid < S_) ? sc[tid] : -1e30f;
    float wm = wred_max(v);
    if (l == 0) red[w] = wm;
    __syncthreads();
    float mx = fmaxf(fmaxf(red[0], red[1]), fmaxf(red[2], red[3]));
    float e = (tid < S_) ? __expf(v - mx) : 0.f;
    float wsum = wred_sum(e);
    if (l == 0) red[4 + w] = wsum;
    __syncthreads();
    float inv = 1.f / (red[4] + red[5] + red[6] + red[7]);
    if (tid < S_) {
        float pv = e * inv;
        sc[tid] = pv;
        prob_cur[(size_t)row * S_ + tid] = pv;
    }
    __syncthreads();

    // ---- ctx ----
    for (int d = tid; d < H_; d += 256) {
        float a0 = 0.f, a1 = 0.f;
        for (int s = 0; s < S_; s += 2) {
            a0 += sc[s] * encb[(size_t)s * H_ + d];
            a1 += sc[s + 1] * encb[(size_t)(s + 1) * H_ + d];
        }
        cs[d] = a0 + a1;
    }
    __syncthreads();

    // ---- switch ----
    float part = 0.f;
    for (int i = tid; i < 3 * H_; i += 256) {
        float xv = (i < H_) ? hs[i] : (i < 2 * H_) ? cs[i - H_] : xs[i - 2 * H_];
        part += xv * Wr[i];
    }
    part = wred_sum(part);
    if (l == 0) red[8 + w] = part;
    __syncthreads();
    if (tid == 0)
        sw_cur[row] = 1.f / (1.f + expf(-(red[8] + red[9] + red[10] + red[11] + Wrb[0])));

    // ---- gate head (ctx of step 0) ----
    if (t == 0 && tid < NB_) {
        float acc = 0.f;
        for (int d = 0; d < H_; ++d) acc += cs[d] * Wg[tid * H_ + d];
        gate_out[(size_t)row * NB_ + tid] = acc + Wgb[tid];
    }
}

// ---------------- final-step finalize ----------------
__global__ __launch_bounds__(256)
void scale_scatter(float* __restrict__ out, const u16* __restrict__ pb,
                   const float* __restrict__ psum, const float* __restrict__ sw,
                   const float* __restrict__ prob, const int* __restrict__ story) {
    const int row = blockIdx.x;
    const int tid = threadIdx.x, w = tid >> 6, l = tid & 63;
    __shared__ float red[4];
    float rs = (tid < NVT_) ? psum[(size_t)row * PSL_ + tid] : 0.f;
    rs = wred_sum(rs);
    if (l == 0) red[w] = rs;
    __syncthreads();
    float denom = red[0] + red[1] + red[2] + red[3];
    float swv = sw[row];
    float scl = swv / denom;
    const u16* ps = pb + (size_t)row * V_;
    float* p = out + ((size_t)row * T_ + (T_ - 1)) * V_;
    for (int v = tid * 8; v < V_; v += 256 * 8) {
        short8 in = *reinterpret_cast<const short8*>(ps + v);
        float4 o0, o1;
        o0.x = bf2f((u16)in[0]) * scl; o0.y = bf2f((u16)in[1]) * scl;
        o0.z = bf2f((u16)in[2]) * scl; o0.w = bf2f((u16)in[3]) * scl;
        o1.x = bf2f((u16)in[4]) * scl; o1.y = bf2f((u16)in[5]) * scl;
        o1.z = bf2f((u16)in[6]) * scl; o1.w = bf2f((u16)in[7]) * scl;
        *reinterpret_cast<float4*>(p + v) = o0;
        *reinterpret_cast<float4*>(p + v + 4) = o1;
    }
    __syncthreads();
    const int batch = row % B_;
    float om = 1.f - swv;
    for (int s = tid; s < S_; s += 256) {
        int tok = story[batch * S_ + s];
        atomicAdd(p + tok, om * prob[(size_t)row * S_ + s]);
    }
}

extern "C" void kernel_launch(void* const* d_in, const int* in_sizes, int n_in,
                              void* d_out, int out_size, void* d_ws, size_t ws_size,
                              hipStream_t stream) {
    const float* eh    = (const float*)d_in[0];
    const float* enc   = (const float*)d_in[1];
    const int*   story = (const int*)d_in[2];
    const int*   tb    = (const int*)d_in[3];
    const int*   dom   = (const int*)d_in[4];
    const int*   sli   = (const int*)d_in[5];
    const float* embW  = (const float*)d_in[6];
    const float* sembW = (const float*)d_in[7];
    const float* Wih   = (const float*)d_in[8];
    const float* Whh   = (const float*)d_in[9];
    const float* bih   = (const float*)d_in[10];
    const float* bhh   = (const float*)d_in[11];
    const float* Wr    = (const float*)d_in[12];
    const float* Wrb   = (const float*)d_in[13];
    const float* Wg    = (const float*)d_in[14];
    const float* Wgb   = (const float*)d_in[15];

    float* out = (float*)d_out;
    float* ws  = (float*)d_ws;

    float* gx_all = ws;                        // [MA_][1200]
    float* gh     = gx_all + (size_t)MA_ * 3 * H_;
    float* hid    = gh + (size_t)BS_ * 3 * H_; // [480][400]
    float* x_all  = hid + (size_t)BS_ * H_;    // [MA_][400]
    float* prob2  = x_all + (size_t)MA_ * H_;  // [2][BS_][S_]
    float* sw2    = prob2 + 2 * BS_ * S_;      // [2][BS_]
    float* psum2  = sw2 + 2 * BS_;             // [2][MP_][PSL_]
    u16* Ab     = (u16*)(psum2 + 2 * (size_t)MP_ * PSL_);  // [MP_][KP_]
    u16* Xb_all = Ab + (size_t)MP_ * KP_;      // [MA_][KP_]
    u16* Wihb   = Xb_all + (size_t)MA_ * KP_;  // [NG_][KP_]
    u16* Whhb   = Wihb + (size_t)NG_ * KP_;    // [NG_][KP_]
    u16* Bb     = Whhb + (size_t)NG_ * KP_;    // [NP_][KP_]
    u16* pb0    = Bb + (size_t)NP_ * KP_;      // [BS_][V_]
    u16* pb1    = pb0 + (size_t)BS_ * V_;      // [BS_][V_] (optional)
    size_t need_base = (size_t)((char*)pb1 - (char*)ws);
    size_t need_full = (size_t)((char*)(pb1 + (size_t)BS_ * V_) - (char*)ws);
    if (ws_size < need_base) return;
    const int dbl = (ws_size >= need_full) ? 1 : 0;

    float* gate_out = out + (size_t)NS_ * B_ * T_ * V_;

    // ---- setup (4 launches) ----
    init_all<<<(MP_ * KP_ + 255) / 256, 256, 0, stream>>>(eh, hid, Ab);
    {
        int tot = (NP_ + 2 * NG_) * (KP_ / 8);
        conv_all<<<(tot + 255) / 256, 256, 0, stream>>>(embW, Wih, Whh, Bb, Wihb, Whhb);
    }
    xall_prep<<<(MA_ * (KP_ / 8) + 255) / 256, 256, 0, stream>>>(tb, embW, sembW, dom, sli,
                                                                 x_all, Xb_all);
    gemm_setup<<<dim3(NG_ / 128, MA_ / 128 + MP_ / 128), 256, 0, stream>>>(
        Xb_all, Ab, Wihb, Whhb, gx_all, gh);

    for (int t = 0; t < T_; ++t) {
        const int cur = t & 1, prev = cur ^ 1;
        float* prob_cur = prob2 + cur * BS_ * S_;
        float* prob_prev = prob2 + prev * BS_ * S_;
        float* sw_cur = sw2 + cur * BS_;
        float* sw_prev = sw2 + prev * BS_;
        float* psum_cur = psum2 + (size_t)cur * MP_ * PSL_;
        float* psum_prev = psum2 + (size_t)prev * MP_ * PSL_;
        u16* pb_cur = dbl ? (cur ? pb1 : pb0) : pb0;
        u16* pb_prev = dbl ? (prev ? pb1 : pb0) : pb0;

        attn_fused<<<BS_, 256, 0, stream>>>(gx_all, gh, bih, bhh, hid, Ab, x_all,
                                            enc, story, Wr, Wrb, Wg, Wgb,
                                            prob_cur, sw_cur, gate_out,
                                            out, pb_prev, psum_prev, sw_prev, prob_prev,
                                            t, dbl ? 0 : 1);
        vocab_gh<<<824, 256, 0, stream>>>(Ab, Bb, Whhb, pb_cur, psum_cur, gh,
                                          pb_prev, psum_prev, sw_prev, prob_prev,
                                          story, out, t, dbl);
    }
    {
        const int last = (T_ - 1) & 1;
        scale_scatter<<<BS_, 256, 0, stream>>>(out, dbl ? (last ? pb1 : pb0) : pb0,
                                               psum2 + (size_t)last * MP_ * PSL_,
                                               sw2 + last * BS_,
                                               prob2 + last * BS_ * S_, story);
    }
}

// Round 10
// 777.916 us; speedup vs baseline: 4.1103x; 1.0374x over previous
//
#include <hip/hip_runtime.h>
#include <math.h>

#define B_   16
#define S_   200
#define H_   400
#define V_   25000
#define T_   8
#define NS_  30
#define NB_  3
#define NSW_ 36
#define BS_  480   // NS_*B_

#define KP_  448   // K padded (7 tiles of 64)
#define MP_  512   // M padded
#define NP_  25088 // vocab N padded (196 tiles of 128)
#define NG_  1280  // gates N padded (10 tiles of 128)
#define MA_  3840  // T_*BS_
#define NVT_ (NP_/128)   // 196 vocab n-tiles
#define PSL_ 200         // psum row stride (196 used)

typedef unsigned short u16;
typedef __attribute__((ext_vector_type(4))) float f32x4;
typedef __attribute__((ext_vector_type(8))) short short8;

__device__ __forceinline__ u16 f2bf(float f) {
    unsigned u = __float_as_uint(f);
    u += 0x7FFFu + ((u >> 16) & 1u);
    return (u16)(u >> 16);
}
__device__ __forceinline__ float bf2f(u16 v) {
    return __uint_as_float(((unsigned)v) << 16);
}
__device__ __forceinline__ float wred_sum(float v) {
    v += __shfl_xor(v, 32); v += __shfl_xor(v, 16); v += __shfl_xor(v, 8);
    v += __shfl_xor(v, 4);  v += __shfl_xor(v, 2);  v += __shfl_xor(v, 1);
    return v;
}
__device__ __forceinline__ float wred_max(float v) {
    v = fmaxf(v, __shfl_xor(v, 32)); v = fmaxf(v, __shfl_xor(v, 16));
    v = fmaxf(v, __shfl_xor(v, 8));  v = fmaxf(v, __shfl_xor(v, 4));
    v = fmaxf(v, __shfl_xor(v, 2));  v = fmaxf(v, __shfl_xor(v, 1));
    return v;
}

__device__ __forceinline__ void gload_lds16(const void* g, void* l) {
    __builtin_amdgcn_global_load_lds(
        (const __attribute__((address_space(1))) void*)g,
        (__attribute__((address_space(3))) void*)l, 16, 0, 0);
}

// 128x128 MFMA tile machinery (used by gemm_setup only).
// NOTE: caller must have `const int tid` in scope before MFMA_SETUP().
#define MFMA_SETUP()                                                          \
    const int wid = tid >> 6, lane = tid & 63;                                \
    const int wr = wid >> 1, wc = wid & 1;                                    \
    f32x4 acc[4][4] = {};                                                     \
    const int sslot = lane & 7;                                               \
    const int srow8 = (lane >> 3) & 7;                                        \
    const int lcol = (sslot ^ srow8) * 8;                                     \
    const int lr = lane & 15, lg = lane >> 4, lx = lane & 7;                  \
    const int sA0 = (lg ^ lx) * 8, sA1 = ((4 + lg) ^ lx) * 8;

#define STAGE_TILE(k0_)                                                       \
    {                                                                         \
        _Pragma("unroll")                                                     \
        for (int is = 0; is < 4; ++is) {                                      \
            gload_lds16(Ag + (size_t)is * 8 * KP_ + (k0_),                    \
                        &As[(wid * 32 + is * 8) * 64]);                       \
            gload_lds16(Bg + (size_t)is * 8 * KP_ + (k0_),                    \
                        &Bs[(wid * 32 + is * 8) * 64]);                       \
        }                                                                     \
    }

#define COMPUTE_TILE()                                                        \
    {                                                                         \
        short8 af[4][2], bfr[4][2];                                           \
        _Pragma("unroll")                                                     \
        for (int i = 0; i < 4; ++i) {                                         \
            int ra = (wr * 64 + i * 16 + lr) * 64;                            \
            af[i][0] = *reinterpret_cast<const short8*>(&As[ra + sA0]);       \
            af[i][1] = *reinterpret_cast<const short8*>(&As[ra + sA1]);       \
            int rb = (wc * 64 + i * 16 + lr) * 64;                            \
            bfr[i][0] = *reinterpret_cast<const short8*>(&Bs[rb + sA0]);      \
            bfr[i][1] = *reinterpret_cast<const short8*>(&Bs[rb + sA1]);      \
        }                                                                     \
        _Pragma("unroll")                                                     \
        for (int h = 0; h < 2; ++h)                                           \
            _Pragma("unroll")                                                 \
            for (int i = 0; i < 4; ++i)                                       \
                _Pragma("unroll")                                             \
                for (int j = 0; j < 4; ++j)                                   \
                    acc[i][j] = __builtin_amdgcn_mfma_f32_16x16x32_bf16(      \
                        af[i][h], bfr[j][h], acc[i][j], 0, 0, 0);             \
    }

#define MFMA_KLOOP_SB()                                                       \
    _Pragma("unroll")                                                         \
    for (int kt = 0; kt < 7; ++kt) {                                          \
        STAGE_TILE(kt * 64);                                                  \
        __syncthreads();                                                      \
        COMPUTE_TILE();                                                       \
        __syncthreads();                                                      \
    }

// ---------------- setup: Ab zero+h0, hid ----------------
__global__ void init_all(const float* __restrict__ eh, float* __restrict__ hid,
                         u16* __restrict__ Ab) {
    int i = blockIdx.x * blockDim.x + threadIdx.x;
    if (i >= MP_ * KP_) return;
    int row = i / KP_, d = i - row * KP_;
    u16 v = 0;
    if (row < BS_ && d < H_) {
        float h = eh[(row % B_) * H_ + d];
        hid[row * H_ + d] = h;
        v = f2bf(h);
    }
    Ab[i] = v;
}

// ---------------- setup: all fp32->bf16 weight conversions ----------------
__device__ __forceinline__ void conv_chunk(const float* __restrict__ src,
                                           u16* __restrict__ dst, int i, int rows) {
    int row = i / (KP_ / 8), c8 = (i - row * (KP_ / 8)) * 8;
    short8 o = {};
    if (row < rows && c8 < H_) {
        const float4* s = reinterpret_cast<const float4*>(src + (size_t)row * H_ + c8);
        float4 a = s[0], b = s[1];
        o[0] = (short)f2bf(a.x); o[1] = (short)f2bf(a.y);
        o[2] = (short)f2bf(a.z); o[3] = (short)f2bf(a.w);
        o[4] = (short)f2bf(b.x); o[5] = (short)f2bf(b.y);
        o[6] = (short)f2bf(b.z); o[7] = (short)f2bf(b.w);
    }
    *reinterpret_cast<short8*>(dst + (size_t)row * KP_ + c8) = o;
}

__global__ void conv_all(const float* __restrict__ embW, const float* __restrict__ Wih,
                         const float* __restrict__ Whh, u16* __restrict__ Bb,
                         u16* __restrict__ Wihb, u16* __restrict__ Whhb) {
    const int CB = NP_ * (KP_ / 8), CG = NG_ * (KP_ / 8);
    int i = blockIdx.x * blockDim.x + threadIdx.x;
    if (i < CB) conv_chunk(embW, Bb, i, V_);
    else if (i < CB + CG) conv_chunk(Wih, Wihb, i - CB, 3 * H_);
    else if (i < CB + 2 * CG) conv_chunk(Whh, Whhb, i - CB - CG, 3 * H_);
}

// ---------------- all-steps teacher-forcing inputs ----------------
__global__ void xall_prep(const int* __restrict__ tb, const float* __restrict__ embW,
                          const float* __restrict__ sembW,
                          const int* __restrict__ dom, const int* __restrict__ sli,
                          float* __restrict__ x_all, u16* __restrict__ Xb_all) {
    int i = blockIdx.x * blockDim.x + threadIdx.x;
    if (i >= MA_ * (KP_ / 8)) return;
    int row = i / (KP_ / 8), c8 = (i - row * (KP_ / 8)) * 8;
    int t = row / BS_, r = row - t * BS_;
    int batch = r % B_, slot = r / B_;
    short8 o = {};
    if (c8 < H_) {
        float4 a, b;
        if (t == 0) {
            const float4* s0 = reinterpret_cast<const float4*>(sembW + dom[slot] * H_ + c8);
            const float4* s1 = reinterpret_cast<const float4*>(sembW + sli[slot] * H_ + c8);
            float4 x0 = s0[0], x1 = s0[1], y0 = s1[0], y1 = s1[1];
            a = make_float4(x0.x + y0.x, x0.y + y0.y, x0.z + y0.z, x0.w + y0.w);
            b = make_float4(x1.x + y1.x, x1.y + y1.y, x1.z + y1.z, x1.w + y1.w);
        } else {
            int tok = tb[(batch * NS_ + slot) * T_ + (t - 1)];
            const float4* s = reinterpret_cast<const float4*>(embW + (size_t)tok * H_ + c8);
            a = s[0]; b = s[1];
        }
        o[0] = (short)f2bf(a.x); o[1] = (short)f2bf(a.y);
        o[2] = (short)f2bf(a.z); o[3] = (short)f2bf(a.w);
        o[4] = (short)f2bf(b.x); o[5] = (short)f2bf(b.y);
        o[6] = (short)f2bf(b.z); o[7] = (short)f2bf(b.w);
        *reinterpret_cast<float4*>(x_all + (size_t)row * H_ + c8) = a;
        *reinterpret_cast<float4*>(x_all + (size_t)row * H_ + c8 + 4) = b;
    }
    *reinterpret_cast<short8*>(Xb_all + (size_t)row * KP_ + c8) = o;
}

// ---------------- setup GEMMs combined: gx_all (y<30) + gh(0) (y>=30) ----------------
__global__ __launch_bounds__(256)
void gemm_setup(const u16* __restrict__ Xb_all, const u16* __restrict__ Abuf,
                const u16* __restrict__ Wihb, const u16* __restrict__ Whhb,
                float* __restrict__ gx_all, float* __restrict__ gh) {
    __shared__ u16 As[128 * 64];
    __shared__ u16 Bs[128 * 64];
    const int tid = threadIdx.x;
    const bool mainp = blockIdx.y < (MA_ / 128);
    const int m0 = (mainp ? blockIdx.y : blockIdx.y - MA_ / 128) * 128;
    const int n0 = blockIdx.x * 128;
    const u16* A = mainp ? Xb_all : Abuf;
    const u16* Bw = mainp ? Wihb : Whhb;
    float* C = mainp ? gx_all : gh;
    const int Mlim = mainp ? MA_ : BS_;

    MFMA_SETUP();
    const u16* Ag = A + (size_t)(m0 + wid * 32 + (lane >> 3)) * KP_ + lcol;
    const u16* Bg = Bw + (size_t)(n0 + wid * 32 + (lane >> 3)) * KP_ + lcol;
    MFMA_KLOOP_SB();

    const int m_base = m0 + wr * 64 + lg * 4;
    const int n_base = n0 + wc * 64 + lr;
    #pragma unroll
    for (int i = 0; i < 4; ++i)
        #pragma unroll
        for (int r = 0; r < 4; ++r) {
            int m = m_base + i * 16 + r;
            if (m >= Mlim) continue;
            #pragma unroll
            for (int j = 0; j < 4; ++j) {
                int n = n_base + j * 16;
                if (n < 3 * H_) C[(size_t)m * 3 * H_ + n] = acc[i][j][r];
            }
        }
}

// ---------------- pure MFMA: vocab (exp->pb + psum) + gh(t+1), 256x128 tile ----------------
// 412 blocks = (196 vocab + 10 gh n-tiles) x 2 m-tiles of 256 rows.
__global__ __launch_bounds__(256, 2)
void vocab_gh(const u16* __restrict__ A, const u16* __restrict__ Bb,
              const u16* __restrict__ Whhb, u16* __restrict__ pb,
              float* __restrict__ psum, float* __restrict__ gh) {
    __shared__ u16 As[256 * 64];    // 32 KB
    __shared__ u16 Bs[128 * 64];    // 16 KB
    __shared__ float sred[2][256];  // 2 KB
    const int bid = blockIdx.x;     // 412 = 8 XCDs: 52,52,52,52,51,51,51,51
    const int tid = threadIdx.x;
    const int xcd = bid & 7, idx = bid >> 3;
    const int lin = (xcd < 4) ? (xcd * 52 + idx) : (208 + (xcd - 4) * 51 + idx);
    const int ntall = lin >> 1, mt = lin & 1;
    const bool isv = (ntall < NVT_);
    const int n0 = (isv ? ntall : ntall - NVT_) * 128;
    const int m0 = mt * 256;
    const u16* Bsrc = isv ? Bb : Whhb;

    const int wid = tid >> 6, lane = tid & 63;
    const int wr = wid >> 1, wc = wid & 1;
    f32x4 acc[8][4] = {};
    const int sslot = lane & 7;
    const int srow8 = (lane >> 3) & 7;
    const int lcol = (sslot ^ srow8) * 8;
    const int lr = lane & 15, lg = lane >> 4, lx = lane & 7;
    const int sA0 = (lg ^ lx) * 8, sA1 = ((4 + lg) ^ lx) * 8;

    const u16* Ag = A + (size_t)(m0 + wid * 64 + (lane >> 3)) * KP_ + lcol;
    const u16* Bg = Bsrc + (size_t)(n0 + wid * 32 + (lane >> 3)) * KP_ + lcol;

    for (int kt = 0; kt < 7; ++kt) {
        const int k0 = kt * 64;
        #pragma unroll
        for (int is = 0; is < 8; ++is)
            gload_lds16(Ag + (size_t)is * 8 * KP_ + k0, &As[(wid * 64 + is * 8) * 64]);
        #pragma unroll
        for (int is = 0; is < 4; ++is)
            gload_lds16(Bg + (size_t)is * 8 * KP_ + k0, &Bs[(wid * 32 + is * 8) * 64]);
        __syncthreads();
        #pragma unroll
        for (int h = 0; h < 2; ++h) {
            const int sA = h ? sA1 : sA0;
            short8 af[8], bf[4];
            #pragma unroll
            for (int i = 0; i < 8; ++i)
                af[i] = *reinterpret_cast<const short8*>(&As[(wr * 128 + i * 16 + lr) * 64 + sA]);
            #pragma unroll
            for (int j = 0; j < 4; ++j)
                bf[j] = *reinterpret_cast<const short8*>(&Bs[(wc * 64 + j * 16 + lr) * 64 + sA]);
            #pragma unroll
            for (int i = 0; i < 8; ++i)
                #pragma unroll
                for (int j = 0; j < 4; ++j)
                    acc[i][j] = __builtin_amdgcn_mfma_f32_16x16x32_bf16(
                        af[i], bf[j], acc[i][j], 0, 0, 0);
        }
        __syncthreads();
    }

    const int m_base = m0 + wr * 128 + lg * 4;
    const int n_base = n0 + wc * 64 + lr;
    if (isv) {
        #pragma unroll
        for (int i = 0; i < 8; ++i) {
            #pragma unroll
            for (int r = 0; r < 4; ++r) {
                int m = m_base + i * 16 + r;
                float js = 0.f;
                #pragma unroll
                for (int j = 0; j < 4; ++j) {
                    int n = n_base + j * 16;
                    float e = __expf(acc[i][j][r]);
                    if (m < BS_ && n < V_) {
                        pb[(size_t)m * V_ + n] = f2bf(e);
                        js += e;
                    }
                }
                js += __shfl_xor(js, 1);
                js += __shfl_xor(js, 2);
                js += __shfl_xor(js, 4);
                js += __shfl_xor(js, 8);
                if ((lane & 15) == 0) sred[wc][m - m0] = js;
            }
        }
        __syncthreads();
        {
            int m = m0 + tid;
            psum[(size_t)m * PSL_ + ntall] = sred[0][tid] + sred[1][tid];
        }
    } else {
        #pragma unroll
        for (int i = 0; i < 8; ++i)
            #pragma unroll
            for (int r = 0; r < 4; ++r) {
                int m = m_base + i * 16 + r;
                if (m >= BS_) continue;
                #pragma unroll
                for (int j = 0; j < 4; ++j) {
                    int n = n_base + j * 16;
                    if (n < 3 * H_) gh[(size_t)m * 3 * H_ + n] = acc[i][j][r];
                }
            }
    }
}

// ---------------- attn (even lin) + finalize t-1 (odd lin), one dispatch ----------------
__global__ __launch_bounds__(256)
void attn_fin(const float* __restrict__ gx_all, const float* __restrict__ gh,
              const float* __restrict__ bih, const float* __restrict__ bhh,
              float* __restrict__ hid, u16* __restrict__ Ab,
              const float* __restrict__ x_all,
              const float* __restrict__ enc, const int* __restrict__ story,
              const float* __restrict__ Wr, const float* __restrict__ Wrb,
              const float* __restrict__ Wg, const float* __restrict__ Wgb,
              float* __restrict__ prob_cur, float* __restrict__ sw_cur,
              float* __restrict__ gate_out,
              float* __restrict__ out, const u16* __restrict__ pb,
              const float* __restrict__ psum, const float* __restrict__ sw_prev,
              const float* __restrict__ prob_prev, int t) {
    const int bid = blockIdx.x;                    // 960 = 8*120
    const int lin = (bid & 7) * 120 + (bid >> 3);
    const int work = lin >> 1, kind = lin & 1;
    const int tid = threadIdx.x, w = tid >> 6, l = tid & 63;
    __shared__ __align__(16) float hs[H_];
    __shared__ __align__(16) float xs[H_];
    __shared__ __align__(16) float cs[H_];
    __shared__ float sc[S_];
    __shared__ float red[16];

    if (kind == 1) {
        // ---- finalize row `work` of step t-1 (reads only step-(t-1) buffers) ----
        if (t == 0) return;
        const int row = work, batch = row % B_;
        float rs = (tid < NVT_) ? psum[(size_t)row * PSL_ + tid] : 0.f;
        rs = wred_sum(rs);
        if (l == 0) red[w] = rs;
        __syncthreads();
        float denom = red[0] + red[1] + red[2] + red[3];
        float swv = sw_prev[row];
        float scl = swv / denom;
        const u16* ps = pb + (size_t)row * V_;
        float* p = out + ((size_t)row * T_ + (t - 1)) * V_;
        for (int v = tid * 8; v < V_; v += 256 * 8) {
            short8 in = *reinterpret_cast<const short8*>(ps + v);
            float4 o0, o1;
            o0.x = bf2f((u16)in[0]) * scl; o0.y = bf2f((u16)in[1]) * scl;
            o0.z = bf2f((u16)in[2]) * scl; o0.w = bf2f((u16)in[3]) * scl;
            o1.x = bf2f((u16)in[4]) * scl; o1.y = bf2f((u16)in[5]) * scl;
            o1.z = bf2f((u16)in[6]) * scl; o1.w = bf2f((u16)in[7]) * scl;
            *reinterpret_cast<float4*>(p + v) = o0;
            *reinterpret_cast<float4*>(p + v + 4) = o1;
        }
        __syncthreads();
        float om = 1.f - swv;
        for (int s = tid; s < S_; s += 256) {
            int tok = story[batch * S_ + s];
            atomicAdd(p + tok, om * prob_prev[(size_t)row * S_ + s]);
        }
        return;
    }

    // ---- attention path: row from `work` (2 batches per XCD) ----
    const int batch = work / 30, slot = work - batch * 30;
    const int row = slot * B_ + batch;

    // GRU cell -> hs (+ hid, bf16 Ab)
    const float* gxr = gx_all + ((size_t)t * BS_ + row) * 3 * H_;
    const float* ghr = gh + (size_t)row * 3 * H_;
    const float* xr  = x_all + ((size_t)t * BS_ + row) * H_;
    for (int d = tid; d < H_; d += 256) {
        float r = 1.f / (1.f + expf(-(gxr[d] + bih[d] + ghr[d] + bhh[d])));
        float z = 1.f / (1.f + expf(-(gxr[H_ + d] + bih[H_ + d] + ghr[H_ + d] + bhh[H_ + d])));
        float n = tanhf(gxr[2 * H_ + d] + bih[2 * H_ + d] + r * (ghr[2 * H_ + d] + bhh[2 * H_ + d]));
        float h = (1.f - z) * n + z * hid[(size_t)row * H_ + d];
        hs[d] = h;
        hid[(size_t)row * H_ + d] = h;
        Ab[(size_t)row * KP_ + d] = f2bf(h);
        xs[d] = xr[d];
    }
    __syncthreads();

    // scores, wave-cooperative (coalesced)
    const float* encb = enc + (size_t)batch * S_ * H_;
    {
        float4 hv1 = *reinterpret_cast<const float4*>(&hs[l * 4]);
        float4 hv2 = make_float4(0.f, 0.f, 0.f, 0.f);
        if (l < 36) hv2 = *reinterpret_cast<const float4*>(&hs[256 + l * 4]);
        for (int k = 0; k < 50; ++k) {
            int s = w * 50 + k;
            const float4* e = reinterpret_cast<const float4*>(encb + (size_t)s * H_);
            float4 ev = e[l];
            float part = ev.x * hv1.x + ev.y * hv1.y + ev.z * hv1.z + ev.w * hv1.w;
            if (l < 36) {
                float4 ev2 = e[64 + l];
                part += ev2.x * hv2.x + ev2.y * hv2.y + ev2.z * hv2.z + ev2.w * hv2.w;
            }
            part = wred_sum(part);
            if (l == 0)
                sc[s] = (story[batch * S_ + s] == 0) ? -1e30f : part;
        }
    }
    __syncthreads();

    // softmax over S_=200
    float v = (tid < S_) ? sc[tid] : -1e30f;
    float wm = wred_max(v);
    if (l == 0) red[w] = wm;
    __syncthreads();
    float mx = fmaxf(fmaxf(red[0], red[1]), fmaxf(red[2], red[3]));
    float e = (tid < S_) ? __expf(v - mx) : 0.f;
    float wsum = wred_sum(e);
    if (l == 0) red[4 + w] = wsum;
    __syncthreads();
    float inv = 1.f / (red[4] + red[5] + red[6] + red[7]);
    if (tid < S_) {
        float pv = e * inv;
        sc[tid] = pv;
        prob_cur[(size_t)row * S_ + tid] = pv;
    }
    __syncthreads();

    // ctx
    for (int d = tid; d < H_; d += 256) {
        float a0 = 0.f, a1 = 0.f;
        for (int s = 0; s < S_; s += 2) {
            a0 += sc[s] * encb[(size_t)s * H_ + d];
            a1 += sc[s + 1] * encb[(size_t)(s + 1) * H_ + d];
        }
        cs[d] = a0 + a1;
    }
    __syncthreads();

    // switch
    float part = 0.f;
    for (int i = tid; i < 3 * H_; i += 256) {
        float xv = (i < H_) ? hs[i] : (i < 2 * H_) ? cs[i - H_] : xs[i - 2 * H_];
        part += xv * Wr[i];
    }
    part = wred_sum(part);
    if (l == 0) red[8 + w] = part;
    __syncthreads();
    if (tid == 0)
        sw_cur[row] = 1.f / (1.f + expf(-(red[8] + red[9] + red[10] + red[11] + Wrb[0])));

    // gate head (ctx of step 0)
    if (t == 0 && tid < NB_) {
        float acc = 0.f;
        for (int d = 0; d < H_; ++d) acc += cs[d] * Wg[tid * H_ + d];
        gate_out[(size_t)row * NB_ + tid] = acc + Wgb[tid];
    }
}

// ---------------- final-step finalize ----------------
__global__ __launch_bounds__(256)
void scale_scatter(float* __restrict__ out, const u16* __restrict__ pb,
                   const float* __restrict__ psum, const float* __restrict__ sw,
                   const float* __restrict__ prob, const int* __restrict__ story) {
    const int row = blockIdx.x;
    const int tid = threadIdx.x, w = tid >> 6, l = tid & 63;
    __shared__ float red[4];
    float rs = (tid < NVT_) ? psum[(size_t)row * PSL_ + tid] : 0.f;
    rs = wred_sum(rs);
    if (l == 0) red[w] = rs;
    __syncthreads();
    float denom = red[0] + red[1] + red[2] + red[3];
    float swv = sw[row];
    float scl = swv / denom;
    const u16* ps = pb + (size_t)row * V_;
    float* p = out + ((size_t)row * T_ + (T_ - 1)) * V_;
    for (int v = tid * 8; v < V_; v += 256 * 8) {
        short8 in = *reinterpret_cast<const short8*>(ps + v);
        float4 o0, o1;
        o0.x = bf2f((u16)in[0]) * scl; o0.y = bf2f((u16)in[1]) * scl;
        o0.z = bf2f((u16)in[2]) * scl; o0.w = bf2f((u16)in[3]) * scl;
        o1.x = bf2f((u16)in[4]) * scl; o1.y = bf2f((u16)in[5]) * scl;
        o1.z = bf2f((u16)in[6]) * scl; o1.w = bf2f((u16)in[7]) * scl;
        *reinterpret_cast<float4*>(p + v) = o0;
        *reinterpret_cast<float4*>(p + v + 4) = o1;
    }
    __syncthreads();
    const int batch = row % B_;
    float om = 1.f - swv;
    for (int s = tid; s < S_; s += 256) {
        int tok = story[batch * S_ + s];
        atomicAdd(p + tok, om * prob[(size_t)row * S_ + s]);
    }
}

extern "C" void kernel_launch(void* const* d_in, const int* in_sizes, int n_in,
                              void* d_out, int out_size, void* d_ws, size_t ws_size,
                              hipStream_t stream) {
    const float* eh    = (const float*)d_in[0];
    const float* enc   = (const float*)d_in[1];
    const int*   story = (const int*)d_in[2];
    const int*   tb    = (const int*)d_in[3];
    const int*   dom   = (const int*)d_in[4];
    const int*   sli   = (const int*)d_in[5];
    const float* embW  = (const float*)d_in[6];
    const float* sembW = (const float*)d_in[7];
    const float* Wih   = (const float*)d_in[8];
    const float* Whh   = (const float*)d_in[9];
    const float* bih   = (const float*)d_in[10];
    const float* bhh   = (const float*)d_in[11];
    const float* Wr    = (const float*)d_in[12];
    const float* Wrb   = (const float*)d_in[13];
    const float* Wg    = (const float*)d_in[14];
    const float* Wgb   = (const float*)d_in[15];

    float* out = (float*)d_out;
    float* ws  = (float*)d_ws;

    float* gx_all = ws;                        // [MA_][1200]
    float* gh     = gx_all + (size_t)MA_ * 3 * H_;
    float* hid    = gh + (size_t)BS_ * 3 * H_; // [480][400]
    float* x_all  = hid + (size_t)BS_ * H_;    // [MA_][400]
    float* prob2  = x_all + (size_t)MA_ * H_;  // [2][BS_][S_]
    float* sw2    = prob2 + 2 * BS_ * S_;      // [2][BS_]
    float* psum   = sw2 + 2 * BS_;             // [MP_][PSL_]
    u16* Ab     = (u16*)(psum + (size_t)MP_ * PSL_);  // [MP_][KP_]
    u16* Xb_all = Ab + (size_t)MP_ * KP_;      // [MA_][KP_]
    u16* Wihb   = Xb_all + (size_t)MA_ * KP_;  // [NG_][KP_]
    u16* Whhb   = Wihb + (size_t)NG_ * KP_;    // [NG_][KP_]
    u16* Bb     = Whhb + (size_t)NG_ * KP_;    // [NP_][KP_]
    u16* pb     = Bb + (size_t)NP_ * KP_;      // [BS_][V_]
    size_t need = (size_t)((char*)(pb + (size_t)BS_ * V_) - (char*)ws);
    if (ws_size < need) return;

    float* gate_out = out + (size_t)NS_ * B_ * T_ * V_;

    // ---- setup (4 launches) ----
    init_all<<<(MP_ * KP_ + 255) / 256, 256, 0, stream>>>(eh, hid, Ab);
    {
        int tot = (NP_ + 2 * NG_) * (KP_ / 8);
        conv_all<<<(tot + 255) / 256, 256, 0, stream>>>(embW, Wih, Whh, Bb, Wihb, Whhb);
    }
    xall_prep<<<(MA_ * (KP_ / 8) + 255) / 256, 256, 0, stream>>>(tb, embW, sembW, dom, sli,
                                                                 x_all, Xb_all);
    gemm_setup<<<dim3(NG_ / 128, MA_ / 128 + MP_ / 128), 256, 0, stream>>>(
        Xb_all, Ab, Wihb, Whhb, gx_all, gh);

    for (int t = 0; t < T_; ++t) {
        const int cur = t & 1, prev = cur ^ 1;
        attn_fin<<<960, 256, 0, stream>>>(gx_all, gh, bih, bhh, hid, Ab, x_all,
                                          enc, story, Wr, Wrb, Wg, Wgb,
                                          prob2 + cur * BS_ * S_, sw2 + cur * BS_,
                                          gate_out, out, pb, psum,
                                          sw2 + prev * BS_, prob2 + prev * BS_ * S_, t);
        vocab_gh<<<412, 256, 0, stream>>>(Ab, Bb, Whhb, pb, psum, gh);
    }
    {
        const int last = (T_ - 1) & 1;
        scale_scatter<<<BS_, 256, 0, stream>>>(out, pb, psum, sw2 + last * BS_,
                                               prob2 + last * BS_ * S_, story);
    }
}